// Round 1
// baseline (2151.992 us; speedup 1.0000x reference)
//
#include <hip/hip_runtime.h>
#include <hip/hip_bf16.h>

#define NCLS 40

// ---------------- CSR build ----------------

__global__ void hist_kernel(const int* __restrict__ dst, int E, int* __restrict__ deg) {
    int i = blockIdx.x * blockDim.x + threadIdx.x;
    int stride = gridDim.x * blockDim.x;
    for (; i < E; i += stride) atomicAdd(&deg[dst[i]], 1);
}

// single-block exclusive scan of deg[0..N) -> offs[0..N], offs[N]=total
__global__ void scan_kernel(const int* __restrict__ deg, int* __restrict__ offs, int N) {
    __shared__ int sums[1024];
    int t = threadIdx.x;
    int chunk = (N + 1023) >> 10;
    int b = t * chunk;
    int e = min(b + chunk, N);
    int s = 0;
    for (int i = b; i < e; ++i) s += deg[i];
    sums[t] = s;
    __syncthreads();
    // Hillis-Steele inclusive scan
    for (int off = 1; off < 1024; off <<= 1) {
        int v = 0;
        if (t >= off) v = sums[t - off];
        __syncthreads();
        sums[t] += v;
        __syncthreads();
    }
    int run = sums[t] - s;  // exclusive prefix of this thread's chunk
    for (int i = b; i < e; ++i) { offs[i] = run; run += deg[i]; }
    if (t == 1023) offs[N] = sums[1023];
}

__global__ void copy_kernel(const int* __restrict__ a, int* __restrict__ b, int N) {
    int i = blockIdx.x * blockDim.x + threadIdx.x;
    if (i < N) b[i] = a[i];
}

__global__ void scatter_kernel(const int* __restrict__ src, const int* __restrict__ dst, int E,
                               int* __restrict__ cursor, int* __restrict__ esrc) {
    int i = blockIdx.x * blockDim.x + threadIdx.x;
    int stride = gridDim.x * blockDim.x;
    for (; i < E; i += stride) {
        int d = dst[i];
        int p = atomicAdd(&cursor[d], 1);
        esrc[p] = src[i];
    }
}

// ---------------- dense X[N,64] @ W[64,FO] ----------------
// one wave per row; lane = output column; X row broadcast via shuffle.
__global__ void gemm_rowwave(const float* __restrict__ X, const float* __restrict__ W,
                             float* __restrict__ out, int N, int FO) {
    int gid = blockIdx.x * blockDim.x + threadIdx.x;
    int row = gid >> 6;
    int lane = threadIdx.x & 63;
    if (row >= N) return;
    float xv = X[(size_t)row * 64 + lane];
    int cl = lane < FO ? lane : 0;
    float acc = 0.f;
#pragma unroll
    for (int k = 0; k < 64; ++k) {
        float xk = __shfl(xv, k, 64);
        acc = fmaf(xk, W[k * FO + cl], acc);
    }
    if (lane < FO) out[(size_t)row * FO + lane] = acc;
}

// ---------------- aggregation: out[n,:] = sum_{e in CSR[n]} t[src_e,:] + b, optional relu
// one wave per node, lane = feature
__global__ void agg_kernel(const float* __restrict__ t, const int* __restrict__ offs,
                           const int* __restrict__ esrc, const float* __restrict__ bias,
                           float* __restrict__ out, int N, int F, int doRelu) {
    int gid = blockIdx.x * blockDim.x + threadIdx.x;
    int node = gid >> 6;
    int lane = threadIdx.x & 63;
    if (node >= N) return;
    int beg = offs[node], end = offs[node + 1];
    int cl = lane < F ? lane : F - 1;
    float acc = 0.f;
    int j = beg;
    // unroll by 2 to get two gathers in flight
    for (; j + 1 < end; j += 2) {
        int s0 = esrc[j];
        int s1 = esrc[j + 1];
        float v0 = t[(size_t)s0 * F + cl];
        float v1 = t[(size_t)s1 * F + cl];
        acc += v0 + v1;
    }
    if (j < end) {
        int s0 = esrc[j];
        acc += t[(size_t)s0 * F + cl];
    }
    if (lane < F) {
        float v = acc + bias[lane];
        if (doRelu) v = fmaxf(v, 0.f);
        out[(size_t)node * F + lane] = v;
    }
}

// ---------------- loss pass ----------------
// per-class sum of exp((double)rep) over rows (no max-sub needed: |rep| << 700),
// per-class label counts, and sum of rep[i, labels[i]].
__global__ void loss_pass(const float* __restrict__ rep, const int* __restrict__ labels, int N,
                          double* __restrict__ colSum, double* __restrict__ pickedSum,
                          int* __restrict__ cnt) {
    const int G = 8;                 // row groups per block
    const int ROWS = 512;            // rows per block
    int t = threadIdx.x;             // blockDim = 320 = G*NCLS (5 waves)
    int c = t % NCLS;
    int g = t / NCLS;
    int base = blockIdx.x * ROWS;
    int lim = min(base + ROWS, N);
    double sumLoc = 0.0, pickLoc = 0.0;
    int cntLoc = 0;
    for (int r = base + g; r < lim; r += G) {
        float v = rep[(size_t)r * NCLS + c];
        sumLoc += exp((double)v);
        if (labels[r] == c) { pickLoc += (double)v; cntLoc++; }
    }
    __shared__ double colP[G][NCLS];
    __shared__ int cntP[G][NCLS];
    __shared__ double waveP[5];
    colP[g][c] = sumLoc;
    cntP[g][c] = cntLoc;
    __syncthreads();
    if (g == 0) {
        double tot = 0.0;
        int ctot = 0;
        for (int gg = 0; gg < G; ++gg) { tot += colP[gg][c]; ctot += cntP[gg][c]; }
        atomicAdd(&colSum[c], tot);
        if (ctot) atomicAdd(&cnt[c], ctot);
    }
    // reduce pickLoc over the block: wave shuffle + 5-wave LDS combine
    double w = pickLoc;
    for (int off = 32; off; off >>= 1) w += __shfl_down(w, off, 64);
    if ((t & 63) == 0) waveP[t >> 6] = w;
    __syncthreads();
    if (t == 0) {
        double s = 0.0;
        for (int i = 0; i < 5; ++i) s += waveP[i];
        atomicAdd(pickedSum, s);
    }
}

__global__ void finalize_kernel(const double* __restrict__ colSum, const int* __restrict__ cnt,
                                const double* __restrict__ pickedSum, int N,
                                float* __restrict__ lossOut) {
    int t = threadIdx.x;  // 64 threads
    double term = 0.0;
    if (t < NCLS) term = (double)cnt[t] * log(colSum[t]);
    for (int off = 32; off; off >>= 1) term += __shfl_down(term, off, 64);
    if (t == 0) {
        double loss = (term - pickedSum[0]) / (double)N;
        lossOut[0] = (float)loss;
    }
}

extern "C" void kernel_launch(void* const* d_in, const int* in_sizes, int n_in,
                              void* d_out, int out_size, void* d_ws, size_t ws_size,
                              hipStream_t stream) {
    const float* features = (const float*)d_in[0];
    const float* W0 = (const float*)d_in[1];
    const float* b0 = (const float*)d_in[2];
    const float* W1 = (const float*)d_in[3];
    const float* b1 = (const float*)d_in[4];
    const float* W2 = (const float*)d_in[5];
    const float* b2 = (const float*)d_in[6];
    const int* src = (const int*)d_in[7];
    const int* dst = (const int*)d_in[8];
    const int* labels = (const int*)d_in[9];
    // d_in[10] = mask: all-true for this problem; count = N.

    const int N = in_sizes[0] / 64;
    const int E = in_sizes[7];
    const int NC = in_sizes[6];  // 40

    char* ws = (char*)d_ws;
    size_t off = 0;
    auto alloc = [&](size_t bytes) -> void* {
        void* p = ws + off;
        off = (off + bytes + 255) & ~(size_t)255;
        return p;
    };
    int* deg    = (int*)alloc((size_t)N * 4);
    int* offs   = (int*)alloc((size_t)(N + 1) * 4);
    int* cursor = (int*)alloc((size_t)N * 4);
    int* esrc   = (int*)alloc((size_t)E * 4);
    float* t0   = (float*)alloc((size_t)N * 64 * 4);
    float* h1   = (float*)alloc((size_t)N * 64 * 4);
    float* h2   = (float*)alloc((size_t)N * 64 * 4);
    char* red   = (char*)alloc(512);
    double* colSum    = (double*)red;          // 320 B
    double* pickedSum = (double*)(red + 320);  // 8 B
    int* cnt          = (int*)(red + 328);     // 160 B

    float* rep = (float*)d_out;
    float* lossOut = rep + (size_t)N * NC;

    hipMemsetAsync(deg, 0, (size_t)N * 4, stream);
    hipMemsetAsync(red, 0, 512, stream);

    // CSR build
    hist_kernel<<<1024, 256, 0, stream>>>(dst, E, deg);
    scan_kernel<<<1, 1024, 0, stream>>>(deg, offs, N);
    copy_kernel<<<(N + 255) / 256, 256, 0, stream>>>(offs, cursor, N);
    scatter_kernel<<<1024, 256, 0, stream>>>(src, dst, E, cursor, esrc);

    const int waveBlocks = (N * 64 + 255) / 256;  // one wave per node/row

    // layer 0: t0 = X@W0 ; h1 = relu(S@t0 + b0)
    gemm_rowwave<<<waveBlocks, 256, 0, stream>>>(features, W0, t0, N, 64);
    agg_kernel<<<waveBlocks, 256, 0, stream>>>(t0, offs, esrc, b0, h1, N, 64, 1);
    // layer 1
    gemm_rowwave<<<waveBlocks, 256, 0, stream>>>(h1, W1, t0, N, 64);
    agg_kernel<<<waveBlocks, 256, 0, stream>>>(t0, offs, esrc, b1, h2, N, 64, 1);
    // layer 2 (no relu), rep -> d_out
    gemm_rowwave<<<waveBlocks, 256, 0, stream>>>(h2, W2, t0, N, NC);
    agg_kernel<<<waveBlocks, 256, 0, stream>>>(t0, offs, esrc, b2, rep, N, NC, 0);

    // loss
    loss_pass<<<(N + 511) / 512, 320, 0, stream>>>(rep, labels, N, colSum, pickedSum, cnt);
    finalize_kernel<<<1, 64, 0, stream>>>(colSum, cnt, pickedSum, N, lossOut);
}

// Round 2
// 799.197 us; speedup vs baseline: 2.6927x; 2.6927x over previous
//
#include <hip/hip_runtime.h>
#include <hip/hip_bf16.h>

#define NCLS 40

// ---------------- CSR build ----------------

__global__ void hist_kernel(const int* __restrict__ dst, int E, int* __restrict__ deg) {
    int i = blockIdx.x * blockDim.x + threadIdx.x;
    int stride = gridDim.x * blockDim.x;
    for (; i < E; i += stride) atomicAdd(&deg[dst[i]], 1);
}

// single-block exclusive scan of deg[0..N) -> offs[0..N], offs[N]=total
__global__ void scan_kernel(const int* __restrict__ deg, int* __restrict__ offs, int N) {
    __shared__ int sums[1024];
    int t = threadIdx.x;
    int chunk = (N + 1023) >> 10;
    int b = t * chunk;
    int e = min(b + chunk, N);
    int s = 0;
    for (int i = b; i < e; ++i) s += deg[i];
    sums[t] = s;
    __syncthreads();
    for (int off = 1; off < 1024; off <<= 1) {
        int v = 0;
        if (t >= off) v = sums[t - off];
        __syncthreads();
        sums[t] += v;
        __syncthreads();
    }
    int run = sums[t] - s;
    for (int i = b; i < e; ++i) { offs[i] = run; run += deg[i]; }
    if (t == 1023) offs[N] = sums[1023];
}

__global__ void copy_kernel(const int* __restrict__ a, int* __restrict__ b, int N) {
    int i = blockIdx.x * blockDim.x + threadIdx.x;
    if (i < N) b[i] = a[i];
}

__global__ void scatter_kernel(const int* __restrict__ src, const int* __restrict__ dst, int E,
                               int* __restrict__ cursor, int* __restrict__ esrc) {
    int i = blockIdx.x * blockDim.x + threadIdx.x;
    int stride = gridDim.x * blockDim.x;
    for (; i < E; i += stride) {
        int d = dst[i];
        int p = atomicAdd(&cursor[d], 1);
        esrc[p] = src[i];
    }
}

// ---------------- dense X[N,64] @ W[64,FO] ----------------
// grid-stride wave-per-row. W column held in 64 VGPRs per lane (loaded once
// per wave). X row broadcast lane->all via v_readlane (VALU pipe; no LDS, no
// global W re-reads). Next row's X prefetched to hide load latency.
__global__ __launch_bounds__(256, 4) void gemm_v2(const float* __restrict__ X,
                                                  const float* __restrict__ W,
                                                  float* __restrict__ out, int N, int FO) {
    int lane = threadIdx.x & 63;
    int waveId = (blockIdx.x * blockDim.x + threadIdx.x) >> 6;
    int nWaves = (gridDim.x * blockDim.x) >> 6;
    int cl = lane < FO ? lane : 0;

    float w[64];
#pragma unroll
    for (int k = 0; k < 64; ++k) w[k] = W[k * FO + cl];

    int row = waveId;
    float xv = (row < N) ? X[(size_t)row * 64 + lane] : 0.f;
    for (; row < N; row += nWaves) {
        int nrow = row + nWaves;
        float nxt = (nrow < N) ? X[(size_t)nrow * 64 + lane] : 0.f;
        float acc = 0.f;
#pragma unroll
        for (int k = 0; k < 64; ++k) {
            float xk = __uint_as_float(__builtin_amdgcn_readlane(__float_as_uint(xv), k));
            acc = fmaf(xk, w[k], acc);
        }
        if (lane < FO) out[(size_t)row * FO + lane] = acc;
        xv = nxt;
    }
}

// ---------------- aggregation (F=64): out[n,:] = sum_e t[esrc,:] + b, opt relu
// one wave per node; lane = (edge slot 0..3) x (col quad 0..15); float4 gathers,
// 4 edges in flight; cross-slot shuffle reduce; lanes 0..15 store float4.
__global__ void agg64_kernel(const float* __restrict__ t, const int* __restrict__ offs,
                             const int* __restrict__ esrc, const float* __restrict__ bias,
                             float* __restrict__ out, int N, int doRelu) {
    int gid = blockIdx.x * blockDim.x + threadIdx.x;
    int node = gid >> 6;
    if (node >= N) return;
    int lane = threadIdx.x & 63;
    int sub = lane >> 4;   // edge slot
    int c4 = lane & 15;    // col quad
    int beg = offs[node], end = offs[node + 1];
    float ax = 0.f, ay = 0.f, az = 0.f, aw = 0.f;
    for (int j = beg + sub; j < end; j += 4) {
        int s = esrc[j];
        const float4 v = *(const float4*)(t + (size_t)s * 64 + c4 * 4);
        ax += v.x; ay += v.y; az += v.z; aw += v.w;
    }
    // reduce across the 4 edge slots (stride 32 then 16)
    ax += __shfl_down(ax, 32, 64); ay += __shfl_down(ay, 32, 64);
    az += __shfl_down(az, 32, 64); aw += __shfl_down(aw, 32, 64);
    ax += __shfl_down(ax, 16, 64); ay += __shfl_down(ay, 16, 64);
    az += __shfl_down(az, 16, 64); aw += __shfl_down(aw, 16, 64);
    if (sub == 0) {
        const float4 b = *(const float4*)(bias + c4 * 4);
        float4 r;
        r.x = ax + b.x; r.y = ay + b.y; r.z = az + b.z; r.w = aw + b.w;
        if (doRelu) {
            r.x = fmaxf(r.x, 0.f); r.y = fmaxf(r.y, 0.f);
            r.z = fmaxf(r.z, 0.f); r.w = fmaxf(r.w, 0.f);
        }
        *(float4*)(out + (size_t)node * 64 + c4 * 4) = r;
    }
}

// generic aggregation (used for F=40 final layer)
__global__ void agg_kernel(const float* __restrict__ t, const int* __restrict__ offs,
                           const int* __restrict__ esrc, const float* __restrict__ bias,
                           float* __restrict__ out, int N, int F, int doRelu) {
    int gid = blockIdx.x * blockDim.x + threadIdx.x;
    int node = gid >> 6;
    int lane = threadIdx.x & 63;
    if (node >= N) return;
    int beg = offs[node], end = offs[node + 1];
    int cl = lane < F ? lane : F - 1;
    float acc = 0.f;
    int j = beg;
    for (; j + 1 < end; j += 2) {
        int s0 = esrc[j];
        int s1 = esrc[j + 1];
        float v0 = t[(size_t)s0 * F + cl];
        float v1 = t[(size_t)s1 * F + cl];
        acc += v0 + v1;
    }
    if (j < end) acc += t[(size_t)esrc[j] * F + cl];
    if (lane < F) {
        float v = acc + bias[lane];
        if (doRelu) v = fmaxf(v, 0.f);
        out[(size_t)node * F + lane] = v;
    }
}

// ---------------- loss ----------------
__global__ void loss_pass(const float* __restrict__ rep, const int* __restrict__ labels, int N,
                          double* __restrict__ colSum, double* __restrict__ pickedSum,
                          int* __restrict__ cnt) {
    const int G = 8;
    const int ROWS = 512;
    int t = threadIdx.x;  // blockDim = 320
    int c = t % NCLS;
    int g = t / NCLS;
    int base = blockIdx.x * ROWS;
    int lim = min(base + ROWS, N);
    double sumLoc = 0.0, pickLoc = 0.0;
    int cntLoc = 0;
    for (int r = base + g; r < lim; r += G) {
        float v = rep[(size_t)r * NCLS + c];
        sumLoc += exp((double)v);
        if (labels[r] == c) { pickLoc += (double)v; cntLoc++; }
    }
    __shared__ double colP[G][NCLS];
    __shared__ int cntP[G][NCLS];
    __shared__ double waveP[5];
    colP[g][c] = sumLoc;
    cntP[g][c] = cntLoc;
    __syncthreads();
    if (g == 0) {
        double tot = 0.0;
        int ctot = 0;
        for (int gg = 0; gg < G; ++gg) { tot += colP[gg][c]; ctot += cntP[gg][c]; }
        atomicAdd(&colSum[c], tot);
        if (ctot) atomicAdd(&cnt[c], ctot);
    }
    double wv = pickLoc;
    for (int off = 32; off; off >>= 1) wv += __shfl_down(wv, off, 64);
    if ((t & 63) == 0) waveP[t >> 6] = wv;
    __syncthreads();
    if (t == 0) {
        double s = 0.0;
        for (int i = 0; i < 5; ++i) s += waveP[i];
        atomicAdd(pickedSum, s);
    }
}

__global__ void finalize_kernel(const double* __restrict__ colSum, const int* __restrict__ cnt,
                                const double* __restrict__ pickedSum, int N,
                                float* __restrict__ lossOut) {
    int t = threadIdx.x;
    double term = 0.0;
    if (t < NCLS) term = (double)cnt[t] * log(colSum[t]);
    for (int off = 32; off; off >>= 1) term += __shfl_down(term, off, 64);
    if (t == 0) lossOut[0] = (float)((term - pickedSum[0]) / (double)N);
}

extern "C" void kernel_launch(void* const* d_in, const int* in_sizes, int n_in,
                              void* d_out, int out_size, void* d_ws, size_t ws_size,
                              hipStream_t stream) {
    const float* features = (const float*)d_in[0];
    const float* W0 = (const float*)d_in[1];
    const float* b0 = (const float*)d_in[2];
    const float* W1 = (const float*)d_in[3];
    const float* b1 = (const float*)d_in[4];
    const float* W2 = (const float*)d_in[5];
    const float* b2 = (const float*)d_in[6];
    const int* src = (const int*)d_in[7];
    const int* dst = (const int*)d_in[8];
    const int* labels = (const int*)d_in[9];

    const int N = in_sizes[0] / 64;
    const int E = in_sizes[7];
    const int NC = in_sizes[6];  // 40

    char* ws = (char*)d_ws;
    size_t off = 0;
    auto alloc = [&](size_t bytes) -> void* {
        void* p = ws + off;
        off = (off + bytes + 255) & ~(size_t)255;
        return p;
    };
    int* deg    = (int*)alloc((size_t)N * 4);
    int* offs   = (int*)alloc((size_t)(N + 1) * 4);
    int* cursor = (int*)alloc((size_t)N * 4);
    int* esrc   = (int*)alloc((size_t)E * 4);
    float* t0   = (float*)alloc((size_t)N * 64 * 4);
    float* h1   = (float*)alloc((size_t)N * 64 * 4);
    float* h2   = (float*)alloc((size_t)N * 64 * 4);
    char* red   = (char*)alloc(512);
    double* colSum    = (double*)red;
    double* pickedSum = (double*)(red + 320);
    int* cnt          = (int*)(red + 328);

    float* rep = (float*)d_out;
    float* lossOut = rep + (size_t)N * NC;

    hipMemsetAsync(deg, 0, (size_t)N * 4, stream);
    hipMemsetAsync(red, 0, 512, stream);

    hist_kernel<<<1024, 256, 0, stream>>>(dst, E, deg);
    scan_kernel<<<1, 1024, 0, stream>>>(deg, offs, N);
    copy_kernel<<<(N + 255) / 256, 256, 0, stream>>>(offs, cursor, N);
    scatter_kernel<<<1024, 256, 0, stream>>>(src, dst, E, cursor, esrc);

    const int nodeWaveBlocks = (N * 64 + 255) / 256;  // one wave per node

    // layer 0
    gemm_v2<<<2048, 256, 0, stream>>>(features, W0, t0, N, 64);
    agg64_kernel<<<nodeWaveBlocks, 256, 0, stream>>>(t0, offs, esrc, b0, h1, N, 1);
    // layer 1
    gemm_v2<<<2048, 256, 0, stream>>>(h1, W1, t0, N, 64);
    agg64_kernel<<<nodeWaveBlocks, 256, 0, stream>>>(t0, offs, esrc, b1, h2, N, 1);
    // layer 2 (no relu) -> rep
    gemm_v2<<<2048, 256, 0, stream>>>(h2, W2, t0, N, NC);
    agg_kernel<<<nodeWaveBlocks, 256, 0, stream>>>(t0, offs, esrc, b2, rep, N, NC, 0);

    // loss
    loss_pass<<<(N + 511) / 512, 320, 0, stream>>>(rep, labels, N, colSum, pickedSum, cnt);
    finalize_kernel<<<1, 64, 0, stream>>>(colSum, cnt, pickedSum, N, lossOut);
}

// Round 3
// 659.413 us; speedup vs baseline: 3.2635x; 1.2120x over previous
//
#include <hip/hip_runtime.h>
#include <hip/hip_bf16.h>

#define NCLS 40

// ---------------- CSR build ----------------

__global__ void hist_kernel(const int* __restrict__ dst, int E, int* __restrict__ deg) {
    int i = blockIdx.x * blockDim.x + threadIdx.x;
    int stride = gridDim.x * blockDim.x;
    for (; i < E; i += stride) atomicAdd(&deg[dst[i]], 1);
}

// level-1: per-block (1024-element slice) sums of deg
__global__ void scan_bsum(const int* __restrict__ deg, int N, int* __restrict__ bsum) {
    int base = blockIdx.x * 1024;
    int t = threadIdx.x;  // 256
    int i0 = base + t * 4;
    int s = 0;
#pragma unroll
    for (int k = 0; k < 4; ++k) {
        int i = i0 + k;
        if (i < N) s += deg[i];
    }
    for (int off = 32; off; off >>= 1) s += __shfl_down(s, off, 64);
    __shared__ int ws[4];
    if ((t & 63) == 0) ws[t >> 6] = s;
    __syncthreads();
    if (t == 0) bsum[blockIdx.x] = ws[0] + ws[1] + ws[2] + ws[3];
}

// level-2: one wave scans B block sums in place (exclusive); writes offs[N]=total
__global__ void scan_mid(int* __restrict__ bsum, int B, int* __restrict__ offs, int N) {
    int t = threadIdx.x;  // 64
    int C = (B + 63) >> 6;
    int b = t * C;
    int e = min(b + C, B);
    int s = 0;
    for (int i = b; i < e; ++i) s += bsum[i];
    int loc = s;
    for (int off = 1; off < 64; off <<= 1) {
        int v = __shfl_up(s, off, 64);
        if (t >= off) s += v;
    }
    int run = s - loc;  // exclusive prefix of this thread's chunk
    for (int i = b; i < e; ++i) { int d = bsum[i]; bsum[i] = run; run += d; }
    if (t == 63) offs[N] = s;
}

// level-3: block-local exclusive scan + block offset; writes offs AND cursor
__global__ void scan_final(const int* __restrict__ deg, const int* __restrict__ bsum, int N,
                           int* __restrict__ offs, int* __restrict__ cursor) {
    int base = blockIdx.x * 1024;
    int t = threadIdx.x;  // 256
    int lane = t & 63;
    int w = t >> 6;
    int i0 = base + t * 4;
    int d0 = 0, d1 = 0, d2 = 0, d3 = 0;
    if (i0 < N)     d0 = deg[i0];
    if (i0 + 1 < N) d1 = deg[i0 + 1];
    if (i0 + 2 < N) d2 = deg[i0 + 2];
    if (i0 + 3 < N) d3 = deg[i0 + 3];
    int loc = d0 + d1 + d2 + d3;
    int s = loc;
    for (int off = 1; off < 64; off <<= 1) {
        int v = __shfl_up(s, off, 64);
        if (lane >= off) s += v;
    }
    __shared__ int ws[4];
    if (lane == 63) ws[w] = s;
    __syncthreads();
    int wofs = 0;
#pragma unroll
    for (int k = 0; k < 4; ++k)
        if (k < w) wofs += ws[k];
    int excl = (s - loc) + wofs + bsum[blockIdx.x];
    if (i0 < N)     { offs[i0] = excl;     cursor[i0] = excl; }
    excl += d0;
    if (i0 + 1 < N) { offs[i0 + 1] = excl; cursor[i0 + 1] = excl; }
    excl += d1;
    if (i0 + 2 < N) { offs[i0 + 2] = excl; cursor[i0 + 2] = excl; }
    excl += d2;
    if (i0 + 3 < N) { offs[i0 + 3] = excl; cursor[i0 + 3] = excl; }
}

__global__ void scatter_kernel(const int* __restrict__ src, const int* __restrict__ dst, int E,
                               int* __restrict__ cursor, int* __restrict__ esrc) {
    int i = blockIdx.x * blockDim.x + threadIdx.x;
    int stride = gridDim.x * blockDim.x;
    for (; i < E; i += stride) {
        int d = dst[i];
        int p = atomicAdd(&cursor[d], 1);
        esrc[p] = src[i];
    }
}

// ---------------- dense X[N,64] @ W[64,FO] ----------------
// grid-stride wave-per-row; W column in 64 VGPRs (loaded once/wave); X row
// broadcast via v_readlane; next row prefetched.
__global__ __launch_bounds__(256, 4) void gemm_v2(const float* __restrict__ X,
                                                  const float* __restrict__ W,
                                                  float* __restrict__ out, int N, int FO) {
    int lane = threadIdx.x & 63;
    int waveId = (blockIdx.x * blockDim.x + threadIdx.x) >> 6;
    int nWaves = (gridDim.x * blockDim.x) >> 6;
    int cl = lane < FO ? lane : 0;

    float w[64];
#pragma unroll
    for (int k = 0; k < 64; ++k) w[k] = W[k * FO + cl];

    int row = waveId;
    float xv = (row < N) ? X[(size_t)row * 64 + lane] : 0.f;
    for (; row < N; row += nWaves) {
        int nrow = row + nWaves;
        float nxt = (nrow < N) ? X[(size_t)nrow * 64 + lane] : 0.f;
        float acc = 0.f;
#pragma unroll
        for (int k = 0; k < 64; ++k) {
            float xk = __uint_as_float(__builtin_amdgcn_readlane(__float_as_uint(xv), k));
            acc = fmaf(xk, w[k], acc);
        }
        if (lane < FO) out[(size_t)row * FO + lane] = acc;
        xv = nxt;
    }
}

// ---------------- aggregation (F=64): one wave/node, 4 edges x 16 col-quads
__global__ void agg64_kernel(const float* __restrict__ t, const int* __restrict__ offs,
                             const int* __restrict__ esrc, const float* __restrict__ bias,
                             float* __restrict__ out, int N, int doRelu) {
    int gid = blockIdx.x * blockDim.x + threadIdx.x;
    int node = gid >> 6;
    if (node >= N) return;
    int lane = threadIdx.x & 63;
    int sub = lane >> 4;
    int c4 = lane & 15;
    int beg = offs[node], end = offs[node + 1];
    float ax = 0.f, ay = 0.f, az = 0.f, aw = 0.f;
    for (int j = beg + sub; j < end; j += 4) {
        int s = esrc[j];
        const float4 v = *(const float4*)(t + (size_t)s * 64 + c4 * 4);
        ax += v.x; ay += v.y; az += v.z; aw += v.w;
    }
    ax += __shfl_down(ax, 32, 64); ay += __shfl_down(ay, 32, 64);
    az += __shfl_down(az, 32, 64); aw += __shfl_down(aw, 32, 64);
    ax += __shfl_down(ax, 16, 64); ay += __shfl_down(ay, 16, 64);
    az += __shfl_down(az, 16, 64); aw += __shfl_down(aw, 16, 64);
    if (sub == 0) {
        const float4 b = *(const float4*)(bias + c4 * 4);
        float4 r;
        r.x = ax + b.x; r.y = ay + b.y; r.z = az + b.z; r.w = aw + b.w;
        if (doRelu) {
            r.x = fmaxf(r.x, 0.f); r.y = fmaxf(r.y, 0.f);
            r.z = fmaxf(r.z, 0.f); r.w = fmaxf(r.w, 0.f);
        }
        *(float4*)(out + (size_t)node * 64 + c4 * 4) = r;
    }
}

// generic aggregation (F=40 final layer)
__global__ void agg_kernel(const float* __restrict__ t, const int* __restrict__ offs,
                           const int* __restrict__ esrc, const float* __restrict__ bias,
                           float* __restrict__ out, int N, int F, int doRelu) {
    int gid = blockIdx.x * blockDim.x + threadIdx.x;
    int node = gid >> 6;
    int lane = threadIdx.x & 63;
    if (node >= N) return;
    int beg = offs[node], end = offs[node + 1];
    int cl = lane < F ? lane : F - 1;
    float acc = 0.f;
    int j = beg;
    for (; j + 1 < end; j += 2) {
        int s0 = esrc[j];
        int s1 = esrc[j + 1];
        float v0 = t[(size_t)s0 * F + cl];
        float v1 = t[(size_t)s1 * F + cl];
        acc += v0 + v1;
    }
    if (j < end) acc += t[(size_t)esrc[j] * F + cl];
    if (lane < F) {
        float v = acc + bias[lane];
        if (doRelu) v = fmaxf(v, 0.f);
        out[(size_t)node * F + lane] = v;
    }
}

// ---------------- loss ----------------
__global__ void loss_pass(const float* __restrict__ rep, const int* __restrict__ labels, int N,
                          double* __restrict__ colSum, double* __restrict__ pickedSum,
                          int* __restrict__ cnt) {
    const int G = 8;
    const int ROWS = 512;
    int t = threadIdx.x;  // blockDim = 320
    int c = t % NCLS;
    int g = t / NCLS;
    int base = blockIdx.x * ROWS;
    int lim = min(base + ROWS, N);
    double sumLoc = 0.0, pickLoc = 0.0;
    int cntLoc = 0;
    for (int r = base + g; r < lim; r += G) {
        float v = rep[(size_t)r * NCLS + c];
        sumLoc += exp((double)v);
        if (labels[r] == c) { pickLoc += (double)v; cntLoc++; }
    }
    __shared__ double colP[G][NCLS];
    __shared__ int cntP[G][NCLS];
    __shared__ double waveP[5];
    colP[g][c] = sumLoc;
    cntP[g][c] = cntLoc;
    __syncthreads();
    if (g == 0) {
        double tot = 0.0;
        int ctot = 0;
        for (int gg = 0; gg < G; ++gg) { tot += colP[gg][c]; ctot += cntP[gg][c]; }
        atomicAdd(&colSum[c], tot);
        if (ctot) atomicAdd(&cnt[c], ctot);
    }
    double wv = pickLoc;
    for (int off = 32; off; off >>= 1) wv += __shfl_down(wv, off, 64);
    if ((t & 63) == 0) waveP[t >> 6] = wv;
    __syncthreads();
    if (t == 0) {
        double s = 0.0;
        for (int i = 0; i < 5; ++i) s += waveP[i];
        atomicAdd(pickedSum, s);
    }
}

__global__ void finalize_kernel(const double* __restrict__ colSum, const int* __restrict__ cnt,
                                const double* __restrict__ pickedSum, int N,
                                float* __restrict__ lossOut) {
    int t = threadIdx.x;
    double term = 0.0;
    if (t < NCLS) term = (double)cnt[t] * log(colSum[t]);
    for (int off = 32; off; off >>= 1) term += __shfl_down(term, off, 64);
    if (t == 0) lossOut[0] = (float)((term - pickedSum[0]) / (double)N);
}

extern "C" void kernel_launch(void* const* d_in, const int* in_sizes, int n_in,
                              void* d_out, int out_size, void* d_ws, size_t ws_size,
                              hipStream_t stream) {
    const float* features = (const float*)d_in[0];
    const float* W0 = (const float*)d_in[1];
    const float* b0 = (const float*)d_in[2];
    const float* W1 = (const float*)d_in[3];
    const float* b1 = (const float*)d_in[4];
    const float* W2 = (const float*)d_in[5];
    const float* b2 = (const float*)d_in[6];
    const int* src = (const int*)d_in[7];
    const int* dst = (const int*)d_in[8];
    const int* labels = (const int*)d_in[9];

    const int N = in_sizes[0] / 64;
    const int E = in_sizes[7];
    const int NC = in_sizes[6];  // 40

    char* ws = (char*)d_ws;
    size_t off = 0;
    auto alloc = [&](size_t bytes) -> void* {
        void* p = ws + off;
        off = (off + bytes + 255) & ~(size_t)255;
        return p;
    };
    int* deg    = (int*)alloc((size_t)N * 4);
    int* offs   = (int*)alloc((size_t)(N + 1) * 4);
    int* cursor = (int*)alloc((size_t)N * 4);
    int* esrc   = (int*)alloc((size_t)E * 4);
    float* t0   = (float*)alloc((size_t)N * 64 * 4);
    float* h1   = (float*)alloc((size_t)N * 64 * 4);
    float* h2   = (float*)alloc((size_t)N * 64 * 4);
    int* bsum   = (int*)alloc(4096);
    char* red   = (char*)alloc(512);
    double* colSum    = (double*)red;
    double* pickedSum = (double*)(red + 320);
    int* cnt          = (int*)(red + 328);

    float* rep = (float*)d_out;
    float* lossOut = rep + (size_t)N * NC;

    const int B = (N + 1023) / 1024;  // scan blocks (98 for N=100000)

    hipMemsetAsync(deg, 0, (size_t)N * 4, stream);
    hipMemsetAsync(red, 0, 512, stream);

    hist_kernel<<<1024, 256, 0, stream>>>(dst, E, deg);
    scan_bsum<<<B, 256, 0, stream>>>(deg, N, bsum);
    scan_mid<<<1, 64, 0, stream>>>(bsum, B, offs, N);
    scan_final<<<B, 256, 0, stream>>>(deg, bsum, N, offs, cursor);
    scatter_kernel<<<1024, 256, 0, stream>>>(src, dst, E, cursor, esrc);

    const int nodeWaveBlocks = (N * 64 + 255) / 256;  // one wave per node

    // layer 0
    gemm_v2<<<2048, 256, 0, stream>>>(features, W0, t0, N, 64);
    agg64_kernel<<<nodeWaveBlocks, 256, 0, stream>>>(t0, offs, esrc, b0, h1, N, 1);
    // layer 1
    gemm_v2<<<2048, 256, 0, stream>>>(h1, W1, t0, N, 64);
    agg64_kernel<<<nodeWaveBlocks, 256, 0, stream>>>(t0, offs, esrc, b1, h2, N, 1);
    // layer 2 (no relu) -> rep
    gemm_v2<<<2048, 256, 0, stream>>>(h2, W2, t0, N, NC);
    agg_kernel<<<nodeWaveBlocks, 256, 0, stream>>>(t0, offs, esrc, b2, rep, N, NC, 0);

    // loss
    loss_pass<<<(N + 511) / 512, 320, 0, stream>>>(rep, labels, N, colSum, pickedSum, cnt);
    finalize_kernel<<<1, 64, 0, stream>>>(colSum, cnt, pickedSum, N, lossOut);
}

// Round 4
// 527.277 us; speedup vs baseline: 4.0813x; 1.2506x over previous
//
#include <hip/hip_runtime.h>
#include <hip/hip_bf16.h>

#define NCLS 40

// ---------------- CSR build: bucketed counting sort ----------------
// Buckets: 1024 consecutive dst nodes per bucket (dst>>10). For N=100K -> 98
// buckets; E=1.7M -> avg 17.4K edges/bucket (~70 KB esrc region, single-XCD).
#define EPB 16384     // edges per level-1 block
#define MAXB1 128     // max level-1 blocks (E <= MAXB1*EPB)
#define MAXNB 104     // max buckets (N <= MAXNB*1024)

// K1: per-(block,bucket) histogram. No global atomics; coalesced count writes.
__global__ void bucket_hist(const int* __restrict__ dst, int E, int nb,
                            int* __restrict__ blockHist) {
    __shared__ int cnt[MAXNB];
    int t = threadIdx.x;  // 256
    for (int i = t; i < nb; i += 256) cnt[i] = 0;
    __syncthreads();
    int base = blockIdx.x * EPB;
    int end = min(base + EPB, E);
    for (int i = base + t; i < end; i += 256) atomicAdd(&cnt[dst[i] >> 10], 1);
    __syncthreads();
    for (int i = t; i < nb; i += 256) blockHist[blockIdx.x * nb + i] = cnt[i];
}

// K2: single block. Column-scan blockHist -> per-(block,bucket) absolute bases,
// bucket offsets, and offs[N]=E.
__global__ void bucket_scan(const int* __restrict__ blockHist, int nB1, int nb,
                            int* __restrict__ blockBase, int* __restrict__ bucketOffs,
                            int* __restrict__ offs, int N, int E) {
    __shared__ int h[MAXB1 * MAXNB];
    __shared__ int btot[MAXNB];
    __shared__ int boffs[MAXNB + 1];
    int t = threadIdx.x;  // 128
    int total = nB1 * nb;
    for (int i = t; i < total; i += 128) h[i] = blockHist[i];
    __syncthreads();
    for (int b = t; b < nb; b += 128) {
        int run = 0;
        for (int i = 0; i < nB1; ++i) { int v = h[i * nb + b]; h[i * nb + b] = run; run += v; }
        btot[b] = run;
    }
    __syncthreads();
    if (t == 0) {
        int run = 0;
        for (int b = 0; b < nb; ++b) { boffs[b] = run; run += btot[b]; }
        boffs[nb] = run;
    }
    __syncthreads();
    for (int b = t; b < nb; b += 128) {
        int bo = boffs[b];
        for (int i = 0; i < nB1; ++i) h[i * nb + b] += bo;
    }
    __syncthreads();
    for (int i = t; i < total; i += 128) blockBase[i] = h[i];
    for (int b = t; b <= nb; b += 128) bucketOffs[b] = boffs[b];
    if (t == 0) offs[N] = E;
}

// K3: place packed edges into reserved per-(block,bucket) runs (~668 B each).
__global__ void bucket_place(const int* __restrict__ src, const int* __restrict__ dst, int E,
                             int nb, const int* __restrict__ blockBase,
                             unsigned* __restrict__ tmp) {
    __shared__ int cur[MAXNB];
    int t = threadIdx.x;  // 256
    for (int i = t; i < nb; i += 256) cur[i] = blockBase[blockIdx.x * nb + i];
    __syncthreads();
    int base = blockIdx.x * EPB;
    int end = min(base + EPB, E);
    for (int i = base + t; i < end; i += 256) {
        int d = dst[i];
        int s = src[i];
        unsigned pack = ((unsigned)(d & 1023) << 17) | (unsigned)s;  // src < 2^17
        int pos = atomicAdd(&cur[d >> 10], 1);
        tmp[pos] = pack;
    }
}

// K4: one block per bucket. LDS node-hist -> block scan -> coalesced offs write,
// then scatter esrc within this bucket's region (single-XCD line ownership).
__global__ __launch_bounds__(512) void bucket_finalize(const unsigned* __restrict__ tmp,
                                                       const int* __restrict__ bucketOffs,
                                                       int N, int* __restrict__ offs,
                                                       int* __restrict__ esrc) {
    __shared__ int cnt[1024];
    __shared__ int wsum[8];
    int b = blockIdx.x;
    int t = threadIdx.x;  // 512
    int bstart = bucketOffs[b], bend = bucketOffs[b + 1];
    cnt[t] = 0;
    cnt[t + 512] = 0;
    __syncthreads();
    for (int i = bstart + t; i < bend; i += 512) atomicAdd(&cnt[tmp[i] >> 17], 1);
    __syncthreads();
    // block-level exclusive scan over 1024 counters (2 per thread)
    int c0 = cnt[2 * t], c1 = cnt[2 * t + 1];
    int s = c0 + c1;
    int lane = t & 63, w = t >> 6;
    int ssc = s;
    for (int off = 1; off < 64; off <<= 1) {
        int v = __shfl_up(ssc, off, 64);
        if (lane >= off) ssc += v;
    }
    if (lane == 63) wsum[w] = ssc;
    __syncthreads();
    int wo = 0;
#pragma unroll
    for (int k = 0; k < 8; ++k)
        if (k < w) wo += wsum[k];
    int excl = (ssc - s) + wo + bstart;  // absolute start for node (b*1024 + 2t)
    __syncthreads();
    int node0 = (b << 10) + 2 * t;
    if (node0 < N) offs[node0] = excl;
    if (node0 + 1 < N) offs[node0 + 1] = excl + c0;
    cnt[2 * t] = excl;
    cnt[2 * t + 1] = excl + c0;
    __syncthreads();
    for (int i = bstart + t; i < bend; i += 512) {
        unsigned p = tmp[i];
        int pos = atomicAdd(&cnt[p >> 17], 1);
        esrc[pos] = (int)(p & 0x1FFFFu);
    }
}

// ---------------- dense X[N,64] @ W[64,FO] ----------------
__global__ __launch_bounds__(256, 4) void gemm_v2(const float* __restrict__ X,
                                                  const float* __restrict__ W,
                                                  float* __restrict__ out, int N, int FO) {
    int lane = threadIdx.x & 63;
    int waveId = (blockIdx.x * blockDim.x + threadIdx.x) >> 6;
    int nWaves = (gridDim.x * blockDim.x) >> 6;
    int cl = lane < FO ? lane : 0;

    float w[64];
#pragma unroll
    for (int k = 0; k < 64; ++k) w[k] = W[k * FO + cl];

    int row = waveId;
    float xv = (row < N) ? X[(size_t)row * 64 + lane] : 0.f;
    for (; row < N; row += nWaves) {
        int nrow = row + nWaves;
        float nxt = (nrow < N) ? X[(size_t)nrow * 64 + lane] : 0.f;
        float acc = 0.f;
#pragma unroll
        for (int k = 0; k < 64; ++k) {
            float xk = __uint_as_float(__builtin_amdgcn_readlane(__float_as_uint(xv), k));
            acc = fmaf(xk, w[k], acc);
        }
        if (lane < FO) out[(size_t)row * FO + lane] = acc;
        xv = nxt;
    }
}

// ---------------- aggregation (F=64): one wave/node, 4 edges x 16 col-quads
__global__ void agg64_kernel(const float* __restrict__ t, const int* __restrict__ offs,
                             const int* __restrict__ esrc, const float* __restrict__ bias,
                             float* __restrict__ out, int N, int doRelu) {
    int gid = blockIdx.x * blockDim.x + threadIdx.x;
    int node = gid >> 6;
    if (node >= N) return;
    int lane = threadIdx.x & 63;
    int sub = lane >> 4;
    int c4 = lane & 15;
    int beg = offs[node], end = offs[node + 1];
    float ax = 0.f, ay = 0.f, az = 0.f, aw = 0.f;
    for (int j = beg + sub; j < end; j += 4) {
        int s = esrc[j];
        const float4 v = *(const float4*)(t + (size_t)s * 64 + c4 * 4);
        ax += v.x; ay += v.y; az += v.z; aw += v.w;
    }
    ax += __shfl_down(ax, 32, 64); ay += __shfl_down(ay, 32, 64);
    az += __shfl_down(az, 32, 64); aw += __shfl_down(aw, 32, 64);
    ax += __shfl_down(ax, 16, 64); ay += __shfl_down(ay, 16, 64);
    az += __shfl_down(az, 16, 64); aw += __shfl_down(aw, 16, 64);
    if (sub == 0) {
        const float4 bb = *(const float4*)(bias + c4 * 4);
        float4 r;
        r.x = ax + bb.x; r.y = ay + bb.y; r.z = az + bb.z; r.w = aw + bb.w;
        if (doRelu) {
            r.x = fmaxf(r.x, 0.f); r.y = fmaxf(r.y, 0.f);
            r.z = fmaxf(r.z, 0.f); r.w = fmaxf(r.w, 0.f);
        }
        *(float4*)(out + (size_t)node * 64 + c4 * 4) = r;
    }
}

// generic aggregation (F=40 final layer)
__global__ void agg_kernel(const float* __restrict__ t, const int* __restrict__ offs,
                           const int* __restrict__ esrc, const float* __restrict__ bias,
                           float* __restrict__ out, int N, int F, int doRelu) {
    int gid = blockIdx.x * blockDim.x + threadIdx.x;
    int node = gid >> 6;
    int lane = threadIdx.x & 63;
    if (node >= N) return;
    int beg = offs[node], end = offs[node + 1];
    int cl = lane < F ? lane : F - 1;
    float acc = 0.f;
    int j = beg;
    for (; j + 1 < end; j += 2) {
        int s0 = esrc[j];
        int s1 = esrc[j + 1];
        float v0 = t[(size_t)s0 * F + cl];
        float v1 = t[(size_t)s1 * F + cl];
        acc += v0 + v1;
    }
    if (j < end) acc += t[(size_t)esrc[j] * F + cl];
    if (lane < F) {
        float v = acc + bias[lane];
        if (doRelu) v = fmaxf(v, 0.f);
        out[(size_t)node * F + lane] = v;
    }
}

// ---------------- loss ----------------
__global__ void loss_pass(const float* __restrict__ rep, const int* __restrict__ labels, int N,
                          double* __restrict__ colSum, double* __restrict__ pickedSum,
                          int* __restrict__ cnt) {
    const int G = 8;
    const int ROWS = 512;
    int t = threadIdx.x;  // blockDim = 320
    int c = t % NCLS;
    int g = t / NCLS;
    int base = blockIdx.x * ROWS;
    int lim = min(base + ROWS, N);
    double sumLoc = 0.0, pickLoc = 0.0;
    int cntLoc = 0;
    for (int r = base + g; r < lim; r += G) {
        float v = rep[(size_t)r * NCLS + c];
        sumLoc += exp((double)v);
        if (labels[r] == c) { pickLoc += (double)v; cntLoc++; }
    }
    __shared__ double colP[G][NCLS];
    __shared__ int cntP[G][NCLS];
    __shared__ double waveP[5];
    colP[g][c] = sumLoc;
    cntP[g][c] = cntLoc;
    __syncthreads();
    if (g == 0) {
        double tot = 0.0;
        int ctot = 0;
        for (int gg = 0; gg < G; ++gg) { tot += colP[gg][c]; ctot += cntP[gg][c]; }
        atomicAdd(&colSum[c], tot);
        if (ctot) atomicAdd(&cnt[c], ctot);
    }
    double wv = pickLoc;
    for (int off = 32; off; off >>= 1) wv += __shfl_down(wv, off, 64);
    if ((t & 63) == 0) waveP[t >> 6] = wv;
    __syncthreads();
    if (t == 0) {
        double s = 0.0;
        for (int i = 0; i < 5; ++i) s += waveP[i];
        atomicAdd(pickedSum, s);
    }
}

__global__ void finalize_kernel(const double* __restrict__ colSum, const int* __restrict__ cnt,
                                const double* __restrict__ pickedSum, int N,
                                float* __restrict__ lossOut) {
    int t = threadIdx.x;
    double term = 0.0;
    if (t < NCLS) term = (double)cnt[t] * log(colSum[t]);
    for (int off = 32; off; off >>= 1) term += __shfl_down(term, off, 64);
    if (t == 0) lossOut[0] = (float)((term - pickedSum[0]) / (double)N);
}

extern "C" void kernel_launch(void* const* d_in, const int* in_sizes, int n_in,
                              void* d_out, int out_size, void* d_ws, size_t ws_size,
                              hipStream_t stream) {
    const float* features = (const float*)d_in[0];
    const float* W0 = (const float*)d_in[1];
    const float* b0 = (const float*)d_in[2];
    const float* W1 = (const float*)d_in[3];
    const float* b1 = (const float*)d_in[4];
    const float* W2 = (const float*)d_in[5];
    const float* b2 = (const float*)d_in[6];
    const int* src = (const int*)d_in[7];
    const int* dst = (const int*)d_in[8];
    const int* labels = (const int*)d_in[9];

    const int N = in_sizes[0] / 64;
    const int E = in_sizes[7];
    const int NC = in_sizes[6];  // 40

    char* ws = (char*)d_ws;
    size_t off = 0;
    auto alloc = [&](size_t bytes) -> void* {
        void* p = ws + off;
        off = (off + bytes + 255) & ~(size_t)255;
        return p;
    };
    int* offs      = (int*)alloc((size_t)(N + 1) * 4);
    int* esrc      = (int*)alloc((size_t)E * 4);
    float* t0      = (float*)alloc((size_t)N * 64 * 4);
    float* h1      = (float*)alloc((size_t)N * 64 * 4);
    float* h2      = (float*)alloc((size_t)N * 64 * 4);
    int* blockHist = (int*)alloc((size_t)MAXB1 * MAXNB * 4);
    int* blockBase = (int*)alloc((size_t)MAXB1 * MAXNB * 4);
    int* bucketOffs= (int*)alloc((size_t)(MAXNB + 1) * 4);
    char* red      = (char*)alloc(512);
    double* colSum    = (double*)red;
    double* pickedSum = (double*)(red + 320);
    int* cntRed       = (int*)(red + 328);

    unsigned* tmp = (unsigned*)t0;  // dead before first gemm writes t0

    float* rep = (float*)d_out;
    float* lossOut = rep + (size_t)N * NC;

    const int nb  = (N + 1023) >> 10;        // 98 buckets
    const int nB1 = (E + EPB - 1) / EPB;     // 104 level-1 blocks

    hipMemsetAsync(red, 0, 512, stream);

    bucket_hist<<<nB1, 256, 0, stream>>>(dst, E, nb, blockHist);
    bucket_scan<<<1, 128, 0, stream>>>(blockHist, nB1, nb, blockBase, bucketOffs, offs, N, E);
    bucket_place<<<nB1, 256, 0, stream>>>(src, dst, E, nb, blockBase, tmp);
    bucket_finalize<<<nb, 512, 0, stream>>>(tmp, bucketOffs, N, offs, esrc);

    const int nodeWaveBlocks = (N * 64 + 255) / 256;  // one wave per node

    // layer 0
    gemm_v2<<<2048, 256, 0, stream>>>(features, W0, t0, N, 64);
    agg64_kernel<<<nodeWaveBlocks, 256, 0, stream>>>(t0, offs, esrc, b0, h1, N, 1);
    // layer 1
    gemm_v2<<<2048, 256, 0, stream>>>(h1, W1, t0, N, 64);
    agg64_kernel<<<nodeWaveBlocks, 256, 0, stream>>>(t0, offs, esrc, b1, h2, N, 1);
    // layer 2 (no relu) -> rep
    gemm_v2<<<2048, 256, 0, stream>>>(h2, W2, t0, N, NC);
    agg_kernel<<<nodeWaveBlocks, 256, 0, stream>>>(t0, offs, esrc, b2, rep, N, NC, 0);

    // loss
    loss_pass<<<(N + 511) / 512, 320, 0, stream>>>(rep, labels, N, colSum, pickedSum, cntRed);
    finalize_kernel<<<1, 64, 0, stream>>>(colSum, cntRed, pickedSum, N, lossOut);
}

// Round 5
// 472.999 us; speedup vs baseline: 4.5497x; 1.1148x over previous
//
#include <hip/hip_runtime.h>
#include <hip/hip_bf16.h>

#define NCLS 40

// ---------------- CSR build: bucketed counting sort ----------------
#define EPB 16384     // edges per level-1 block
#define MAXB1 128     // max level-1 blocks (E <= MAXB1*EPB)
#define MAXNB 104     // max buckets (N <= MAXNB*1024)

__global__ void bucket_hist(const int* __restrict__ dst, int E, int nb,
                            int* __restrict__ blockHist) {
    __shared__ int cnt[MAXNB];
    int t = threadIdx.x;  // 256
    for (int i = t; i < nb; i += 256) cnt[i] = 0;
    __syncthreads();
    int base = blockIdx.x * EPB;
    int end = min(base + EPB, E);
    for (int i = base + t; i < end; i += 256) atomicAdd(&cnt[dst[i] >> 10], 1);
    __syncthreads();
    for (int i = t; i < nb; i += 256) blockHist[blockIdx.x * nb + i] = cnt[i];
}

__global__ void bucket_scan(const int* __restrict__ blockHist, int nB1, int nb,
                            int* __restrict__ blockBase, int* __restrict__ bucketOffs,
                            int* __restrict__ offs, int N, int E) {
    __shared__ int h[MAXB1 * MAXNB];
    __shared__ int btot[MAXNB];
    __shared__ int boffs[MAXNB + 1];
    int t = threadIdx.x;  // 128
    int total = nB1 * nb;
    for (int i = t; i < total; i += 128) h[i] = blockHist[i];
    __syncthreads();
    for (int b = t; b < nb; b += 128) {
        int run = 0;
        for (int i = 0; i < nB1; ++i) { int v = h[i * nb + b]; h[i * nb + b] = run; run += v; }
        btot[b] = run;
    }
    __syncthreads();
    if (t == 0) {
        int run = 0;
        for (int b = 0; b < nb; ++b) { boffs[b] = run; run += btot[b]; }
        boffs[nb] = run;
    }
    __syncthreads();
    for (int b = t; b < nb; b += 128) {
        int bo = boffs[b];
        for (int i = 0; i < nB1; ++i) h[i * nb + b] += bo;
    }
    __syncthreads();
    for (int i = t; i < total; i += 128) blockBase[i] = h[i];
    for (int b = t; b <= nb; b += 128) bucketOffs[b] = boffs[b];
    if (t == 0) offs[N] = E;
}

__global__ void bucket_place(const int* __restrict__ src, const int* __restrict__ dst, int E,
                             int nb, const int* __restrict__ blockBase,
                             unsigned* __restrict__ tmp) {
    __shared__ int cur[MAXNB];
    int t = threadIdx.x;  // 256
    for (int i = t; i < nb; i += 256) cur[i] = blockBase[blockIdx.x * nb + i];
    __syncthreads();
    int base = blockIdx.x * EPB;
    int end = min(base + EPB, E);
    for (int i = base + t; i < end; i += 256) {
        int d = dst[i];
        int s = src[i];
        unsigned pack = ((unsigned)(d & 1023) << 17) | (unsigned)s;  // src < 2^17
        int pos = atomicAdd(&cur[d >> 10], 1);
        tmp[pos] = pack;
    }
}

__global__ __launch_bounds__(512) void bucket_finalize(const unsigned* __restrict__ tmp,
                                                       const int* __restrict__ bucketOffs,
                                                       int N, int* __restrict__ offs,
                                                       int* __restrict__ esrc) {
    __shared__ int cnt[1024];
    __shared__ int wsum[8];
    int b = blockIdx.x;
    int t = threadIdx.x;  // 512
    int bstart = bucketOffs[b], bend = bucketOffs[b + 1];
    cnt[t] = 0;
    cnt[t + 512] = 0;
    __syncthreads();
    for (int i = bstart + t; i < bend; i += 512) atomicAdd(&cnt[tmp[i] >> 17], 1);
    __syncthreads();
    int c0 = cnt[2 * t], c1 = cnt[2 * t + 1];
    int s = c0 + c1;
    int lane = t & 63, w = t >> 6;
    int ssc = s;
    for (int off = 1; off < 64; off <<= 1) {
        int v = __shfl_up(ssc, off, 64);
        if (lane >= off) ssc += v;
    }
    if (lane == 63) wsum[w] = ssc;
    __syncthreads();
    int wo = 0;
#pragma unroll
    for (int k = 0; k < 8; ++k)
        if (k < w) wo += wsum[k];
    int excl = (ssc - s) + wo + bstart;
    __syncthreads();
    int node0 = (b << 10) + 2 * t;
    if (node0 < N) offs[node0] = excl;
    if (node0 + 1 < N) offs[node0 + 1] = excl + c0;
    cnt[2 * t] = excl;
    cnt[2 * t + 1] = excl + c0;
    __syncthreads();
    for (int i = bstart + t; i < bend; i += 512) {
        unsigned p = tmp[i];
        int pos = atomicAdd(&cnt[p >> 17], 1);
        esrc[pos] = (int)(p & 0x1FFFFu);
    }
}

// ---------------- dense X[N,64] @ W[64,FO] (+ optional bias) ----------------
__global__ __launch_bounds__(256, 4) void gemm_v2(const float* __restrict__ X,
                                                  const float* __restrict__ W,
                                                  const float* __restrict__ bias,
                                                  float* __restrict__ out, int N, int FO) {
    int lane = threadIdx.x & 63;
    int waveId = (blockIdx.x * blockDim.x + threadIdx.x) >> 6;
    int nWaves = (gridDim.x * blockDim.x) >> 6;
    int cl = lane < FO ? lane : 0;

    float w[64];
#pragma unroll
    for (int k = 0; k < 64; ++k) w[k] = W[k * FO + cl];
    float bv = 0.f;
    if (bias != nullptr && lane < FO) bv = bias[lane];

    int row = waveId;
    float xv = (row < N) ? X[(size_t)row * 64 + lane] : 0.f;
    for (; row < N; row += nWaves) {
        int nrow = row + nWaves;
        float nxt = (nrow < N) ? X[(size_t)nrow * 64 + lane] : 0.f;
        float acc = bv;
#pragma unroll
        for (int k = 0; k < 64; ++k) {
            float xk = __uint_as_float(__builtin_amdgcn_readlane(__float_as_uint(xv), k));
            acc = fmaf(xk, w[k], acc);
        }
        if (lane < FO) out[(size_t)row * FO + lane] = acc;
        xv = nxt;
    }
}

// ---------------- aggregation (F=64): one wave/node, 4 edge slots x 16 quads,
// edge loop unrolled x2 -> 8 float4 gathers in flight per wave.
// bias==nullptr -> plain sum (no bias/relu).
__global__ void agg64_kernel(const float* __restrict__ t, const int* __restrict__ offs,
                             const int* __restrict__ esrc, const float* __restrict__ bias,
                             float* __restrict__ out, int N, int doRelu) {
    int gid = blockIdx.x * blockDim.x + threadIdx.x;
    int node = gid >> 6;
    if (node >= N) return;
    int lane = threadIdx.x & 63;
    int sub = lane >> 4;
    int c4 = lane & 15;
    int beg = offs[node], end = offs[node + 1];
    float a0x = 0.f, a0y = 0.f, a0z = 0.f, a0w = 0.f;
    float a1x = 0.f, a1y = 0.f, a1z = 0.f, a1w = 0.f;
    int j = beg + sub;
    for (; j + 4 < end; j += 8) {
        int s0 = esrc[j];
        int s1 = esrc[j + 4];
        const float4 v0 = *(const float4*)(t + (size_t)s0 * 64 + c4 * 4);
        const float4 v1 = *(const float4*)(t + (size_t)s1 * 64 + c4 * 4);
        a0x += v0.x; a0y += v0.y; a0z += v0.z; a0w += v0.w;
        a1x += v1.x; a1y += v1.y; a1z += v1.z; a1w += v1.w;
    }
    if (j < end) {
        int s0 = esrc[j];
        const float4 v0 = *(const float4*)(t + (size_t)s0 * 64 + c4 * 4);
        a0x += v0.x; a0y += v0.y; a0z += v0.z; a0w += v0.w;
    }
    float ax = a0x + a1x, ay = a0y + a1y, az = a0z + a1z, aw = a0w + a1w;
    ax += __shfl_down(ax, 32, 64); ay += __shfl_down(ay, 32, 64);
    az += __shfl_down(az, 32, 64); aw += __shfl_down(aw, 32, 64);
    ax += __shfl_down(ax, 16, 64); ay += __shfl_down(ay, 16, 64);
    az += __shfl_down(az, 16, 64); aw += __shfl_down(aw, 16, 64);
    if (sub == 0) {
        float4 r;
        if (bias != nullptr) {
            const float4 bb = *(const float4*)(bias + c4 * 4);
            r.x = ax + bb.x; r.y = ay + bb.y; r.z = az + bb.z; r.w = aw + bb.w;
        } else {
            r.x = ax; r.y = ay; r.z = az; r.w = aw;
        }
        if (doRelu) {
            r.x = fmaxf(r.x, 0.f); r.y = fmaxf(r.y, 0.f);
            r.z = fmaxf(r.z, 0.f); r.w = fmaxf(r.w, 0.f);
        }
        *(float4*)(out + (size_t)node * 64 + c4 * 4) = r;
    }
}

// ---------------- loss ----------------
__global__ void loss_pass(const float* __restrict__ rep, const int* __restrict__ labels, int N,
                          double* __restrict__ colSum, double* __restrict__ pickedSum,
                          int* __restrict__ cnt) {
    const int G = 8;
    const int ROWS = 512;
    int t = threadIdx.x;  // blockDim = 320
    int c = t % NCLS;
    int g = t / NCLS;
    int base = blockIdx.x * ROWS;
    int lim = min(base + ROWS, N);
    double sumLoc = 0.0, pickLoc = 0.0;
    int cntLoc = 0;
    for (int r = base + g; r < lim; r += G) {
        float v = rep[(size_t)r * NCLS + c];
        sumLoc += exp((double)v);
        if (labels[r] == c) { pickLoc += (double)v; cntLoc++; }
    }
    __shared__ double colP[G][NCLS];
    __shared__ int cntP[G][NCLS];
    __shared__ double waveP[5];
    colP[g][c] = sumLoc;
    cntP[g][c] = cntLoc;
    __syncthreads();
    if (g == 0) {
        double tot = 0.0;
        int ctot = 0;
        for (int gg = 0; gg < G; ++gg) { tot += colP[gg][c]; ctot += cntP[gg][c]; }
        atomicAdd(&colSum[c], tot);
        if (ctot) atomicAdd(&cnt[c], ctot);
    }
    double wv = pickLoc;
    for (int off = 32; off; off >>= 1) wv += __shfl_down(wv, off, 64);
    if ((t & 63) == 0) waveP[t >> 6] = wv;
    __syncthreads();
    if (t == 0) {
        double s = 0.0;
        for (int i = 0; i < 5; ++i) s += waveP[i];
        atomicAdd(pickedSum, s);
    }
}

__global__ void finalize_kernel(const double* __restrict__ colSum, const int* __restrict__ cnt,
                                const double* __restrict__ pickedSum, int N,
                                float* __restrict__ lossOut) {
    int t = threadIdx.x;
    double term = 0.0;
    if (t < NCLS) term = (double)cnt[t] * log(colSum[t]);
    for (int off = 32; off; off >>= 1) term += __shfl_down(term, off, 64);
    if (t == 0) lossOut[0] = (float)((term - pickedSum[0]) / (double)N);
}

extern "C" void kernel_launch(void* const* d_in, const int* in_sizes, int n_in,
                              void* d_out, int out_size, void* d_ws, size_t ws_size,
                              hipStream_t stream) {
    const float* features = (const float*)d_in[0];
    const float* W0 = (const float*)d_in[1];
    const float* b0 = (const float*)d_in[2];
    const float* W1 = (const float*)d_in[3];
    const float* b1 = (const float*)d_in[4];
    const float* W2 = (const float*)d_in[5];
    const float* b2 = (const float*)d_in[6];
    const int* src = (const int*)d_in[7];
    const int* dst = (const int*)d_in[8];
    const int* labels = (const int*)d_in[9];

    const int N = in_sizes[0] / 64;
    const int E = in_sizes[7];
    const int NC = in_sizes[6];  // 40

    char* ws = (char*)d_ws;
    size_t off = 0;
    auto alloc = [&](size_t bytes) -> void* {
        void* p = ws + off;
        off = (off + bytes + 255) & ~(size_t)255;
        return p;
    };
    int* offs      = (int*)alloc((size_t)(N + 1) * 4);
    int* esrc      = (int*)alloc((size_t)E * 4);
    float* t0      = (float*)alloc((size_t)N * 64 * 4);
    float* h1      = (float*)alloc((size_t)N * 64 * 4);
    float* h2      = (float*)alloc((size_t)N * 64 * 4);
    int* blockHist = (int*)alloc((size_t)MAXB1 * MAXNB * 4);
    int* blockBase = (int*)alloc((size_t)MAXB1 * MAXNB * 4);
    int* bucketOffs= (int*)alloc((size_t)(MAXNB + 1) * 4);
    char* red      = (char*)alloc(512);
    double* colSum    = (double*)red;
    double* pickedSum = (double*)(red + 320);
    int* cntRed       = (int*)(red + 328);

    unsigned* tmp = (unsigned*)t0;  // dead before first gemm writes t0

    float* rep = (float*)d_out;
    float* lossOut = rep + (size_t)N * NC;

    const int nb  = (N + 1023) >> 10;
    const int nB1 = (E + EPB - 1) / EPB;

    hipMemsetAsync(red, 0, 512, stream);

    bucket_hist<<<nB1, 256, 0, stream>>>(dst, E, nb, blockHist);
    bucket_scan<<<1, 128, 0, stream>>>(blockHist, nB1, nb, blockBase, bucketOffs, offs, N, E);
    bucket_place<<<nB1, 256, 0, stream>>>(src, dst, E, nb, blockBase, tmp);
    bucket_finalize<<<nb, 512, 0, stream>>>(tmp, bucketOffs, N, offs, esrc);

    const int nodeWaveBlocks = (N * 64 + 255) / 256;  // one wave per node

    // layer 0: t0 = X@W0 ; h1 = relu(S@t0 + b0)
    gemm_v2<<<2048, 256, 0, stream>>>(features, W0, nullptr, t0, N, 64);
    agg64_kernel<<<nodeWaveBlocks, 256, 0, stream>>>(t0, offs, esrc, b0, h1, N, 1);
    // layer 1: t0 = h1@W1 ; h2 = relu(S@t0 + b1)
    gemm_v2<<<2048, 256, 0, stream>>>(h1, W1, nullptr, t0, N, 64);
    agg64_kernel<<<nodeWaveBlocks, 256, 0, stream>>>(t0, offs, esrc, b1, h2, N, 1);
    // layer 2 (aggregate-first): t0 = S@h2 ; rep = t0@W2 + b2
    agg64_kernel<<<nodeWaveBlocks, 256, 0, stream>>>(h2, offs, esrc, nullptr, t0, N, 0);
    gemm_v2<<<2048, 256, 0, stream>>>(t0, W2, b2, rep, N, NC);

    // loss
    loss_pass<<<(N + 511) / 512, 320, 0, stream>>>(rep, labels, N, colSum, pickedSum, cntRed);
    finalize_kernel<<<1, 64, 0, stream>>>(colSum, cntRed, pickedSum, N, lossOut);
}

// Round 6
// 426.888 us; speedup vs baseline: 5.0411x; 1.1080x over previous
//
#include <hip/hip_runtime.h>
#include <hip/hip_bf16.h>
#include <hip/hip_fp16.h>

#define NCLS 40

typedef __attribute__((ext_vector_type(8))) _Float16 half8;

// ---------------- CSR build: bucketed counting sort ----------------
#define EPB 16384     // edges per level-1 block
#define MAXB1 128     // max level-1 blocks (E <= MAXB1*EPB)
#define MAXNB 104     // max buckets (N <= MAXNB*1024)

__global__ void bucket_hist(const int* __restrict__ dst, int E, int nb,
                            int* __restrict__ blockHist) {
    __shared__ int cnt[MAXNB];
    int t = threadIdx.x;  // 256
    for (int i = t; i < nb; i += 256) cnt[i] = 0;
    __syncthreads();
    int base = blockIdx.x * EPB;
    int end = min(base + EPB, E);
    for (int i = base + t; i < end; i += 256) atomicAdd(&cnt[dst[i] >> 10], 1);
    __syncthreads();
    for (int i = t; i < nb; i += 256) blockHist[blockIdx.x * nb + i] = cnt[i];
}

__global__ void bucket_scan(const int* __restrict__ blockHist, int nB1, int nb,
                            int* __restrict__ blockBase, int* __restrict__ bucketOffs,
                            int* __restrict__ offs, int N, int E) {
    __shared__ int h[MAXB1 * MAXNB];
    __shared__ int btot[MAXNB];
    __shared__ int boffs[MAXNB + 1];
    int t = threadIdx.x;  // 128
    int total = nB1 * nb;
    for (int i = t; i < total; i += 128) h[i] = blockHist[i];
    __syncthreads();
    for (int b = t; b < nb; b += 128) {
        int run = 0;
        for (int i = 0; i < nB1; ++i) { int v = h[i * nb + b]; h[i * nb + b] = run; run += v; }
        btot[b] = run;
    }
    __syncthreads();
    if (t == 0) {
        int run = 0;
        for (int b = 0; b < nb; ++b) { boffs[b] = run; run += btot[b]; }
        boffs[nb] = run;
    }
    __syncthreads();
    for (int b = t; b < nb; b += 128) {
        int bo = boffs[b];
        for (int i = 0; i < nB1; ++i) h[i * nb + b] += bo;
    }
    __syncthreads();
    for (int i = t; i < total; i += 128) blockBase[i] = h[i];
    for (int b = t; b <= nb; b += 128) bucketOffs[b] = boffs[b];
    if (t == 0) offs[N] = E;
}

__global__ void bucket_place(const int* __restrict__ src, const int* __restrict__ dst, int E,
                             int nb, const int* __restrict__ blockBase,
                             unsigned* __restrict__ tmp) {
    __shared__ int cur[MAXNB];
    int t = threadIdx.x;  // 256
    for (int i = t; i < nb; i += 256) cur[i] = blockBase[blockIdx.x * nb + i];
    __syncthreads();
    int base = blockIdx.x * EPB;
    int end = min(base + EPB, E);
    for (int i = base + t; i < end; i += 256) {
        int d = dst[i];
        int s = src[i];
        unsigned pack = ((unsigned)(d & 1023) << 17) | (unsigned)s;  // src < 2^17
        int pos = atomicAdd(&cur[d >> 10], 1);
        tmp[pos] = pack;
    }
}

__global__ __launch_bounds__(512) void bucket_finalize(const unsigned* __restrict__ tmp,
                                                       const int* __restrict__ bucketOffs,
                                                       int N, int* __restrict__ offs,
                                                       int* __restrict__ esrc) {
    __shared__ int cnt[1024];
    __shared__ int wsum[8];
    int b = blockIdx.x;
    int t = threadIdx.x;  // 512
    int bstart = bucketOffs[b], bend = bucketOffs[b + 1];
    cnt[t] = 0;
    cnt[t + 512] = 0;
    __syncthreads();
    for (int i = bstart + t; i < bend; i += 512) atomicAdd(&cnt[tmp[i] >> 17], 1);
    __syncthreads();
    int c0 = cnt[2 * t], c1 = cnt[2 * t + 1];
    int s = c0 + c1;
    int lane = t & 63, w = t >> 6;
    int ssc = s;
    for (int off = 1; off < 64; off <<= 1) {
        int v = __shfl_up(ssc, off, 64);
        if (lane >= off) ssc += v;
    }
    if (lane == 63) wsum[w] = ssc;
    __syncthreads();
    int wo = 0;
#pragma unroll
    for (int k = 0; k < 8; ++k)
        if (k < w) wo += wsum[k];
    int excl = (ssc - s) + wo + bstart;
    __syncthreads();
    int node0 = (b << 10) + 2 * t;
    if (node0 < N) offs[node0] = excl;
    if (node0 + 1 < N) offs[node0 + 1] = excl + c0;
    cnt[2 * t] = excl;
    cnt[2 * t + 1] = excl + c0;
    __syncthreads();
    for (int i = bstart + t; i < bend; i += 512) {
        unsigned p = tmp[i];
        int pos = atomicAdd(&cnt[p >> 17], 1);
        esrc[pos] = (int)(p & 0x1FFFFu);
    }
}

// ---------------- dense X[N,64] @ W[64,FO] (+opt bias); out fp32 or fp16 ----
__global__ __launch_bounds__(256, 4) void gemm_v3(const float* __restrict__ X,
                                                  const float* __restrict__ W,
                                                  const float* __restrict__ bias,
                                                  void* __restrict__ out, int N, int FO,
                                                  int outHalf) {
    int lane = threadIdx.x & 63;
    int waveId = (blockIdx.x * blockDim.x + threadIdx.x) >> 6;
    int nWaves = (gridDim.x * blockDim.x) >> 6;
    int cl = lane < FO ? lane : 0;

    float w[64];
#pragma unroll
    for (int k = 0; k < 64; ++k) w[k] = W[k * FO + cl];
    float bv = 0.f;
    if (bias != nullptr && lane < FO) bv = bias[lane];

    float* outF = (float*)out;
    _Float16* outH = (_Float16*)out;

    int row = waveId;
    float xv = (row < N) ? X[(size_t)row * 64 + lane] : 0.f;
    for (; row < N; row += nWaves) {
        int nrow = row + nWaves;
        float nxt = (nrow < N) ? X[(size_t)nrow * 64 + lane] : 0.f;
        float acc = bv;
#pragma unroll
        for (int k = 0; k < 64; ++k) {
            float xk = __uint_as_float(__builtin_amdgcn_readlane(__float_as_uint(xv), k));
            acc = fmaf(xk, w[k], acc);
        }
        if (lane < FO) {
            if (outHalf) outH[(size_t)row * FO + lane] = (_Float16)acc;
            else         outF[(size_t)row * FO + lane] = acc;
        }
        xv = nxt;
    }
}

// ---------------- aggregation over fp16 rows [N,64] -------------------------
// one wave/node: 8 edge slots x 8 col-octets; 16 B loads (8 halfs) per lane,
// unrolled x2 (2 loads in flight/lane); fp32 accumulate; out fp32 or fp16.
__global__ void agg64h_kernel(const _Float16* __restrict__ t, const int* __restrict__ offs,
                              const int* __restrict__ esrc, const float* __restrict__ bias,
                              void* __restrict__ out, int N, int doRelu, int outHalf) {
    int gid = blockIdx.x * blockDim.x + threadIdx.x;
    int node = gid >> 6;
    if (node >= N) return;
    int lane = threadIdx.x & 63;
    int sub = lane >> 3;   // edge slot 0..7
    int c8 = lane & 7;     // col octet (8 halfs = 16 B)
    int beg = offs[node], end = offs[node + 1];
    float a[8];
#pragma unroll
    for (int k = 0; k < 8; ++k) a[k] = 0.f;
    int j = beg + sub;
    for (; j + 8 < end; j += 16) {
        int s0 = esrc[j];
        int s1 = esrc[j + 8];
        half8 v0 = *(const half8*)(t + (size_t)s0 * 64 + c8 * 8);
        half8 v1 = *(const half8*)(t + (size_t)s1 * 64 + c8 * 8);
#pragma unroll
        for (int k = 0; k < 8; ++k) a[k] += (float)v0[k] + (float)v1[k];
    }
    if (j < end) {
        int s0 = esrc[j];
        half8 v0 = *(const half8*)(t + (size_t)s0 * 64 + c8 * 8);
#pragma unroll
        for (int k = 0; k < 8; ++k) a[k] += (float)v0[k];
    }
    // reduce across the 8 edge slots (lane strides 32, 16, 8)
#pragma unroll
    for (int k = 0; k < 8; ++k) {
        a[k] += __shfl_down(a[k], 32, 64);
        a[k] += __shfl_down(a[k], 16, 64);
        a[k] += __shfl_down(a[k], 8, 64);
    }
    if (sub == 0) {
        if (bias != nullptr) {
#pragma unroll
            for (int k = 0; k < 8; ++k) a[k] += bias[c8 * 8 + k];
        }
        if (doRelu) {
#pragma unroll
            for (int k = 0; k < 8; ++k) a[k] = fmaxf(a[k], 0.f);
        }
        if (outHalf) {
            half8 hv;
#pragma unroll
            for (int k = 0; k < 8; ++k) hv[k] = (_Float16)a[k];
            *(half8*)((_Float16*)out + (size_t)node * 64 + c8 * 8) = hv;
        } else {
            float* po = (float*)out + (size_t)node * 64 + c8 * 8;
            float4 r0 = {a[0], a[1], a[2], a[3]};
            float4 r1 = {a[4], a[5], a[6], a[7]};
            *(float4*)(po) = r0;
            *(float4*)(po + 4) = r1;
        }
    }
}

// ---------------- loss ----------------
__global__ void loss_pass(const float* __restrict__ rep, const int* __restrict__ labels, int N,
                          double* __restrict__ colSum, double* __restrict__ pickedSum,
                          int* __restrict__ cnt) {
    const int G = 8;
    const int ROWS = 512;
    int t = threadIdx.x;  // blockDim = 320
    int c = t % NCLS;
    int g = t / NCLS;
    int base = blockIdx.x * ROWS;
    int lim = min(base + ROWS, N);
    double sumLoc = 0.0, pickLoc = 0.0;
    int cntLoc = 0;
    for (int r = base + g; r < lim; r += G) {
        float v = rep[(size_t)r * NCLS + c];
        sumLoc += exp((double)v);
        if (labels[r] == c) { pickLoc += (double)v; cntLoc++; }
    }
    __shared__ double colP[G][NCLS];
    __shared__ int cntP[G][NCLS];
    __shared__ double waveP[5];
    colP[g][c] = sumLoc;
    cntP[g][c] = cntLoc;
    __syncthreads();
    if (g == 0) {
        double tot = 0.0;
        int ctot = 0;
        for (int gg = 0; gg < G; ++gg) { tot += colP[gg][c]; ctot += cntP[gg][c]; }
        atomicAdd(&colSum[c], tot);
        if (ctot) atomicAdd(&cnt[c], ctot);
    }
    double wv = pickLoc;
    for (int off = 32; off; off >>= 1) wv += __shfl_down(wv, off, 64);
    if ((t & 63) == 0) waveP[t >> 6] = wv;
    __syncthreads();
    if (t == 0) {
        double s = 0.0;
        for (int i = 0; i < 5; ++i) s += waveP[i];
        atomicAdd(pickedSum, s);
    }
}

__global__ void finalize_kernel(const double* __restrict__ colSum, const int* __restrict__ cnt,
                                const double* __restrict__ pickedSum, int N,
                                float* __restrict__ lossOut) {
    int t = threadIdx.x;
    double term = 0.0;
    if (t < NCLS) term = (double)cnt[t] * log(colSum[t]);
    for (int off = 32; off; off >>= 1) term += __shfl_down(term, off, 64);
    if (t == 0) lossOut[0] = (float)((term - pickedSum[0]) / (double)N);
}

extern "C" void kernel_launch(void* const* d_in, const int* in_sizes, int n_in,
                              void* d_out, int out_size, void* d_ws, size_t ws_size,
                              hipStream_t stream) {
    const float* features = (const float*)d_in[0];
    const float* W0 = (const float*)d_in[1];
    const float* b0 = (const float*)d_in[2];
    const float* W1 = (const float*)d_in[3];
    const float* b1 = (const float*)d_in[4];
    const float* W2 = (const float*)d_in[5];
    const float* b2 = (const float*)d_in[6];
    const int* src = (const int*)d_in[7];
    const int* dst = (const int*)d_in[8];
    const int* labels = (const int*)d_in[9];

    const int N = in_sizes[0] / 64;
    const int E = in_sizes[7];
    const int NC = in_sizes[6];  // 40

    char* ws = (char*)d_ws;
    size_t off = 0;
    auto alloc = [&](size_t bytes) -> void* {
        void* p = ws + off;
        off = (off + bytes + 255) & ~(size_t)255;
        return p;
    };
    int* offs      = (int*)alloc((size_t)(N + 1) * 4);
    int* esrc      = (int*)alloc((size_t)E * 4);
    _Float16* t0   = (_Float16*)alloc((size_t)N * 64 * 2);   // fp16 gather target; aliases tmp
    float* h1      = (float*)alloc((size_t)N * 64 * 4);      // fp32; reused as t2
    _Float16* h2   = (_Float16*)alloc((size_t)N * 64 * 2);   // fp16 gather target
    int* blockHist = (int*)alloc((size_t)MAXB1 * MAXNB * 4);
    int* blockBase = (int*)alloc((size_t)MAXB1 * MAXNB * 4);
    int* bucketOffs= (int*)alloc((size_t)(MAXNB + 1) * 4);
    char* red      = (char*)alloc(512);
    double* colSum    = (double*)red;
    double* pickedSum = (double*)(red + 320);
    int* cntRed       = (int*)(red + 328);

    unsigned* tmp = (unsigned*)t0;  // E*4 = 6.8 MB <= N*64*2 = 12.8 MB; dead before gemm
    float* t2 = h1;                 // h1 dead after layer-1 gemm

    float* rep = (float*)d_out;
    float* lossOut = rep + (size_t)N * NC;

    const int nb  = (N + 1023) >> 10;
    const int nB1 = (E + EPB - 1) / EPB;

    hipMemsetAsync(red, 0, 512, stream);

    bucket_hist<<<nB1, 256, 0, stream>>>(dst, E, nb, blockHist);
    bucket_scan<<<1, 128, 0, stream>>>(blockHist, nB1, nb, blockBase, bucketOffs, offs, N, E);
    bucket_place<<<nB1, 256, 0, stream>>>(src, dst, E, nb, blockBase, tmp);
    bucket_finalize<<<nb, 512, 0, stream>>>(tmp, bucketOffs, N, offs, esrc);

    const int nodeWaveBlocks = (N * 64 + 255) / 256;  // one wave per node

    // layer 0: t0 = fp16(X@W0) ; h1 = relu(S@t0 + b0)  [h1 fp32]
    gemm_v3<<<2048, 256, 0, stream>>>(features, W0, nullptr, t0, N, 64, 1);
    agg64h_kernel<<<nodeWaveBlocks, 256, 0, stream>>>(t0, offs, esrc, b0, h1, N, 1, 0);
    // layer 1: t0 = fp16(h1@W1) ; h2 = fp16(relu(S@t0 + b1))
    gemm_v3<<<2048, 256, 0, stream>>>(h1, W1, nullptr, t0, N, 64, 1);
    agg64h_kernel<<<nodeWaveBlocks, 256, 0, stream>>>(t0, offs, esrc, b1, h2, N, 1, 1);
    // layer 2 (aggregate-first): t2 = S@h2 [fp32] ; rep = t2@W2 + b2
    agg64h_kernel<<<nodeWaveBlocks, 256, 0, stream>>>(h2, offs, esrc, nullptr, t2, N, 0, 0);
    gemm_v3<<<2048, 256, 0, stream>>>(t2, W2, b2, rep, N, NC, 0);

    // loss
    loss_pass<<<(N + 511) / 512, 320, 0, stream>>>(rep, labels, N, colSum, pickedSum, cntRed);
    finalize_kernel<<<1, 64, 0, stream>>>(colSum, cntRed, pickedSum, N, lossOut);
}

// Round 7
// 411.708 us; speedup vs baseline: 5.2270x; 1.0369x over previous
//
#include <hip/hip_runtime.h>
#include <hip/hip_bf16.h>
#include <hip/hip_fp16.h>

#define NCLS 40

typedef __attribute__((ext_vector_type(8))) _Float16 half8;

// ---------------- CSR build: bucketed counting sort ----------------
#define EPB 16384     // edges per level-1 block
#define MAXB1 128     // max level-1 blocks (E <= MAXB1*EPB)
#define MAXNB 104     // max buckets (N <= MAXNB*1024)

__global__ void bucket_hist(const int* __restrict__ dst, int E, int nb,
                            int* __restrict__ blockHist) {
    __shared__ int cnt[MAXNB];
    int t = threadIdx.x;  // 256
    for (int i = t; i < nb; i += 256) cnt[i] = 0;
    __syncthreads();
    int base = blockIdx.x * EPB;
    int end = min(base + EPB, E);
    for (int i = base + t; i < end; i += 256) atomicAdd(&cnt[dst[i] >> 10], 1);
    __syncthreads();
    for (int i = t; i < nb; i += 256) blockHist[blockIdx.x * nb + i] = cnt[i];
}

// also zeroes the 512-byte reduction scratch (replaces a memset dispatch)
__global__ void bucket_scan(const int* __restrict__ blockHist, int nB1, int nb,
                            int* __restrict__ blockBase, int* __restrict__ bucketOffs,
                            int* __restrict__ offs, int N, int E, int* __restrict__ red32) {
    __shared__ int h[MAXB1 * MAXNB];
    __shared__ int btot[MAXNB];
    __shared__ int boffs[MAXNB + 1];
    int t = threadIdx.x;  // 128
    if (t < 128) red32[t] = 0;
    int total = nB1 * nb;
    for (int i = t; i < total; i += 128) h[i] = blockHist[i];
    __syncthreads();
    for (int b = t; b < nb; b += 128) {
        int run = 0;
        for (int i = 0; i < nB1; ++i) { int v = h[i * nb + b]; h[i * nb + b] = run; run += v; }
        btot[b] = run;
    }
    __syncthreads();
    if (t == 0) {
        int run = 0;
        for (int b = 0; b < nb; ++b) { boffs[b] = run; run += btot[b]; }
        boffs[nb] = run;
    }
    __syncthreads();
    for (int b = t; b < nb; b += 128) {
        int bo = boffs[b];
        for (int i = 0; i < nB1; ++i) h[i * nb + b] += bo;
    }
    __syncthreads();
    for (int i = t; i < total; i += 128) blockBase[i] = h[i];
    for (int b = t; b <= nb; b += 128) bucketOffs[b] = boffs[b];
    if (t == 0) offs[N] = E;
}

__global__ void bucket_place(const int* __restrict__ src, const int* __restrict__ dst, int E,
                             int nb, const int* __restrict__ blockBase,
                             unsigned* __restrict__ tmp) {
    __shared__ int cur[MAXNB];
    int t = threadIdx.x;  // 256
    for (int i = t; i < nb; i += 256) cur[i] = blockBase[blockIdx.x * nb + i];
    __syncthreads();
    int base = blockIdx.x * EPB;
    int end = min(base + EPB, E);
    for (int i = base + t; i < end; i += 256) {
        int d = dst[i];
        int s = src[i];
        unsigned pack = ((unsigned)(d & 1023) << 17) | (unsigned)s;  // src < 2^17
        int pos = atomicAdd(&cur[d >> 10], 1);
        tmp[pos] = pack;
    }
}

__global__ __launch_bounds__(512) void bucket_finalize(const unsigned* __restrict__ tmp,
                                                       const int* __restrict__ bucketOffs,
                                                       int N, int* __restrict__ offs,
                                                       int* __restrict__ esrc) {
    __shared__ int cnt[1024];
    __shared__ int wsum[8];
    int b = blockIdx.x;
    int t = threadIdx.x;  // 512
    int bstart = bucketOffs[b], bend = bucketOffs[b + 1];
    cnt[t] = 0;
    cnt[t + 512] = 0;
    __syncthreads();
    for (int i = bstart + t; i < bend; i += 512) atomicAdd(&cnt[tmp[i] >> 17], 1);
    __syncthreads();
    int c0 = cnt[2 * t], c1 = cnt[2 * t + 1];
    int s = c0 + c1;
    int lane = t & 63, w = t >> 6;
    int ssc = s;
    for (int off = 1; off < 64; off <<= 1) {
        int v = __shfl_up(ssc, off, 64);
        if (lane >= off) ssc += v;
    }
    if (lane == 63) wsum[w] = ssc;
    __syncthreads();
    int wo = 0;
#pragma unroll
    for (int k = 0; k < 8; ++k)
        if (k < w) wo += wsum[k];
    int excl = (ssc - s) + wo + bstart;
    __syncthreads();
    int node0 = (b << 10) + 2 * t;
    if (node0 < N) offs[node0] = excl;
    if (node0 + 1 < N) offs[node0 + 1] = excl + c0;
    cnt[2 * t] = excl;
    cnt[2 * t + 1] = excl + c0;
    __syncthreads();
    for (int i = bstart + t; i < bend; i += 512) {
        unsigned p = tmp[i];
        int pos = atomicAdd(&cnt[p >> 17], 1);
        esrc[pos] = (int)(p & 0x1FFFFu);
    }
}

// ---------------- dense X[N,64] @ W[64,64] -> fp16 out ----------------------
__global__ __launch_bounds__(256, 4) void gemm_h(const float* __restrict__ X,
                                                 const float* __restrict__ W,
                                                 _Float16* __restrict__ out, int N) {
    int lane = threadIdx.x & 63;
    int waveId = (blockIdx.x * blockDim.x + threadIdx.x) >> 6;
    int nWaves = (gridDim.x * blockDim.x) >> 6;

    float w[64];
#pragma unroll
    for (int k = 0; k < 64; ++k) w[k] = W[k * 64 + lane];

    int row = waveId;
    float xv = (row < N) ? X[(size_t)row * 64 + lane] : 0.f;
    for (; row < N; row += nWaves) {
        int nrow = row + nWaves;
        float nxt = (nrow < N) ? X[(size_t)nrow * 64 + lane] : 0.f;
        float acc = 0.f;
#pragma unroll
        for (int k = 0; k < 64; ++k) {
            float xk = __uint_as_float(__builtin_amdgcn_readlane(__float_as_uint(xv), k));
            acc = fmaf(xk, w[k], acc);
        }
        out[(size_t)row * 64 + lane] = (_Float16)acc;
        xv = nxt;
    }
}

// ---------------- plain aggregation over fp16 rows [N,64] -------------------
// one wave/node: 8 edge slots x 8 col-octets; fp32 accumulate; fp16 out.
__global__ void agg64h_kernel(const _Float16* __restrict__ t, const int* __restrict__ offs,
                              const int* __restrict__ esrc, const float* __restrict__ bias,
                              _Float16* __restrict__ out, int N) {
    int gid = blockIdx.x * blockDim.x + threadIdx.x;
    int node = gid >> 6;
    if (node >= N) return;
    int lane = threadIdx.x & 63;
    int sub = lane >> 3;   // edge slot 0..7
    int c8 = lane & 7;     // col octet (8 halfs = 16 B)
    int beg = offs[node], end = offs[node + 1];
    float a[8];
#pragma unroll
    for (int k = 0; k < 8; ++k) a[k] = 0.f;
    int j = beg + sub;
    for (; j + 8 < end; j += 16) {
        int s0 = esrc[j];
        int s1 = esrc[j + 8];
        half8 v0 = *(const half8*)(t + (size_t)s0 * 64 + c8 * 8);
        half8 v1 = *(const half8*)(t + (size_t)s1 * 64 + c8 * 8);
#pragma unroll
        for (int k = 0; k < 8; ++k) a[k] += (float)v0[k] + (float)v1[k];
    }
    if (j < end) {
        int s0 = esrc[j];
        half8 v0 = *(const half8*)(t + (size_t)s0 * 64 + c8 * 8);
#pragma unroll
        for (int k = 0; k < 8; ++k) a[k] += (float)v0[k];
    }
#pragma unroll
    for (int k = 0; k < 8; ++k) {
        a[k] += __shfl_down(a[k], 32, 64);
        a[k] += __shfl_down(a[k], 16, 64);
        a[k] += __shfl_down(a[k], 8, 64);
    }
    if (sub == 0) {
        half8 hv;
#pragma unroll
        for (int k = 0; k < 8; ++k) {
            float v = fmaxf(a[k] + bias[c8 * 8 + k], 0.f);  // bias + relu
            hv[k] = (_Float16)v;
        }
        *(half8*)(out + (size_t)node * 64 + c8 * 8) = hv;
    }
}

// ---------------- fused aggregation + GEMV epilogue -------------------------
// grid-stride wave-per-node. Gather fp16 rows, reduce to full row on lanes
// 0..7 (a[8] each), optional bias+relu, then y[lane] = row @ W[:,lane] via
// readlane broadcast against VGPR-resident W column; optional gemm bias.
__global__ __launch_bounds__(256, 4) void fused_agg_gemm(
        const _Float16* __restrict__ t, const int* __restrict__ offs,
        const int* __restrict__ esrc, const float* __restrict__ aggBias, int doRelu,
        const float* __restrict__ W, const float* __restrict__ gemmBias, int FO,
        void* __restrict__ out, int outHalf, int N) {
    int lane = threadIdx.x & 63;
    int waveId = (blockIdx.x * blockDim.x + threadIdx.x) >> 6;
    int nWaves = (gridDim.x * blockDim.x) >> 6;
    int sub = lane >> 3;
    int c8 = lane & 7;
    int cl = lane < FO ? lane : 0;

    float w[64];
#pragma unroll
    for (int k = 0; k < 64; ++k) w[k] = W[k * FO + cl];
    float gb = 0.f;
    if (gemmBias != nullptr && lane < FO) gb = gemmBias[lane];
    float ab[8];
#pragma unroll
    for (int k = 0; k < 8; ++k) ab[k] = (aggBias != nullptr) ? aggBias[c8 * 8 + k] : 0.f;

    float* outF = (float*)out;
    _Float16* outH = (_Float16*)out;

    for (int node = waveId; node < N; node += nWaves) {
        int beg = offs[node], end = offs[node + 1];
        float a[8];
#pragma unroll
        for (int k = 0; k < 8; ++k) a[k] = 0.f;
        int j = beg + sub;
        for (; j + 8 < end; j += 16) {
            int s0 = esrc[j];
            int s1 = esrc[j + 8];
            half8 v0 = *(const half8*)(t + (size_t)s0 * 64 + c8 * 8);
            half8 v1 = *(const half8*)(t + (size_t)s1 * 64 + c8 * 8);
#pragma unroll
            for (int k = 0; k < 8; ++k) a[k] += (float)v0[k] + (float)v1[k];
        }
        if (j < end) {
            int s0 = esrc[j];
            half8 v0 = *(const half8*)(t + (size_t)s0 * 64 + c8 * 8);
#pragma unroll
            for (int k = 0; k < 8; ++k) a[k] += (float)v0[k];
        }
#pragma unroll
        for (int k = 0; k < 8; ++k) {
            a[k] += __shfl_down(a[k], 32, 64);
            a[k] += __shfl_down(a[k], 16, 64);
            a[k] += __shfl_down(a[k], 8, 64);
            a[k] += ab[k];                       // only lanes 0..7 matter below
            if (doRelu) a[k] = fmaxf(a[k], 0.f);
        }
        // GEMV: y = gb + sum_k row[k] * w[k]; row[k] lives on lane k>>3, reg k&7
        float y = gb;
#pragma unroll
        for (int k = 0; k < 64; ++k) {
            float rk = __uint_as_float(
                __builtin_amdgcn_readlane(__float_as_uint(a[k & 7]), k >> 3));
            y = fmaf(rk, w[k], y);
        }
        if (lane < FO) {
            if (outHalf) outH[(size_t)node * FO + lane] = (_Float16)y;
            else         outF[(size_t)node * FO + lane] = y;
        }
    }
}

// ---------------- loss ----------------
__global__ void loss_pass(const float* __restrict__ rep, const int* __restrict__ labels, int N,
                          double* __restrict__ colSum, double* __restrict__ pickedSum,
                          int* __restrict__ cnt) {
    const int G = 8;
    const int ROWS = 512;
    int t = threadIdx.x;  // blockDim = 320
    int c = t % NCLS;
    int g = t / NCLS;
    int base = blockIdx.x * ROWS;
    int lim = min(base + ROWS, N);
    double sumLoc = 0.0, pickLoc = 0.0;
    int cntLoc = 0;
    for (int r = base + g; r < lim; r += G) {
        float v = rep[(size_t)r * NCLS + c];
        sumLoc += exp((double)v);
        if (labels[r] == c) { pickLoc += (double)v; cntLoc++; }
    }
    __shared__ double colP[G][NCLS];
    __shared__ int cntP[G][NCLS];
    __shared__ double waveP[5];
    colP[g][c] = sumLoc;
    cntP[g][c] = cntLoc;
    __syncthreads();
    if (g == 0) {
        double tot = 0.0;
        int ctot = 0;
        for (int gg = 0; gg < G; ++gg) { tot += colP[gg][c]; ctot += cntP[gg][c]; }
        atomicAdd(&colSum[c], tot);
        if (ctot) atomicAdd(&cnt[c], ctot);
    }
    double wv = pickLoc;
    for (int off = 32; off; off >>= 1) wv += __shfl_down(wv, off, 64);
    if ((t & 63) == 0) waveP[t >> 6] = wv;
    __syncthreads();
    if (t == 0) {
        double s = 0.0;
        for (int i = 0; i < 5; ++i) s += waveP[i];
        atomicAdd(pickedSum, s);
    }
}

__global__ void finalize_kernel(const double* __restrict__ colSum, const int* __restrict__ cnt,
                                const double* __restrict__ pickedSum, int N,
                                float* __restrict__ lossOut) {
    int t = threadIdx.x;
    double term = 0.0;
    if (t < NCLS) term = (double)cnt[t] * log(colSum[t]);
    for (int off = 32; off; off >>= 1) term += __shfl_down(term, off, 64);
    if (t == 0) lossOut[0] = (float)((term - pickedSum[0]) / (double)N);
}

extern "C" void kernel_launch(void* const* d_in, const int* in_sizes, int n_in,
                              void* d_out, int out_size, void* d_ws, size_t ws_size,
                              hipStream_t stream) {
    const float* features = (const float*)d_in[0];
    const float* W0 = (const float*)d_in[1];
    const float* b0 = (const float*)d_in[2];
    const float* W1 = (const float*)d_in[3];
    const float* b1 = (const float*)d_in[4];
    const float* W2 = (const float*)d_in[5];
    const float* b2 = (const float*)d_in[6];
    const int* src = (const int*)d_in[7];
    const int* dst = (const int*)d_in[8];
    const int* labels = (const int*)d_in[9];

    const int N = in_sizes[0] / 64;
    const int E = in_sizes[7];
    const int NC = in_sizes[6];  // 40

    char* ws = (char*)d_ws;
    size_t off = 0;
    auto alloc = [&](size_t bytes) -> void* {
        void* p = ws + off;
        off = (off + bytes + 255) & ~(size_t)255;
        return p;
    };
    int* offs      = (int*)alloc((size_t)(N + 1) * 4);
    int* esrc      = (int*)alloc((size_t)E * 4);
    _Float16* t0   = (_Float16*)alloc((size_t)N * 64 * 2);   // gemm0 out
    _Float16* t1   = (_Float16*)alloc((size_t)N * 64 * 2);   // fusedA out; aliases tmp
    _Float16* h2   = (_Float16*)alloc((size_t)N * 64 * 2);   // aggB out
    int* blockHist = (int*)alloc((size_t)MAXB1 * MAXNB * 4);
    int* blockBase = (int*)alloc((size_t)MAXB1 * MAXNB * 4);
    int* bucketOffs= (int*)alloc((size_t)(MAXNB + 1) * 4);
    char* red      = (char*)alloc(512);
    double* colSum    = (double*)red;
    double* pickedSum = (double*)(red + 320);
    int* cntRed       = (int*)(red + 328);

    unsigned* tmp = (unsigned*)t1;  // E*4 = 6.8 MB <= N*64*2 = 12.8 MB; dead before fusedA

    float* rep = (float*)d_out;
    float* lossOut = rep + (size_t)N * NC;

    const int nb  = (N + 1023) >> 10;
    const int nB1 = (E + EPB - 1) / EPB;

    bucket_hist<<<nB1, 256, 0, stream>>>(dst, E, nb, blockHist);
    bucket_scan<<<1, 128, 0, stream>>>(blockHist, nB1, nb, blockBase, bucketOffs, offs, N, E,
                                       (int*)red);
    bucket_place<<<nB1, 256, 0, stream>>>(src, dst, E, nb, blockBase, tmp);
    bucket_finalize<<<nb, 512, 0, stream>>>(tmp, bucketOffs, N, offs, esrc);

    const int nodeWaveBlocks = (N * 64 + 255) / 256;  // one wave per node

    // layer 0 gemm: t0 = fp16(X@W0)
    gemm_h<<<2048, 256, 0, stream>>>(features, W0, t0, N);
    // fused layer0-agg + layer1-gemm: t1 = fp16(relu(S@t0 + b0) @ W1)
    fused_agg_gemm<<<2048, 256, 0, stream>>>(t0, offs, esrc, b0, 1, W1, nullptr, 64, t1, 1, N);
    // layer1 agg: h2 = fp16(relu(S@t1 + b1))
    agg64h_kernel<<<nodeWaveBlocks, 256, 0, stream>>>(t1, offs, esrc, b1, h2, N);
    // fused layer2: rep = (S@h2)@W2 + b2   [fp32 out]
    fused_agg_gemm<<<2048, 256, 0, stream>>>(h2, offs, esrc, nullptr, 0, W2, b2, NC, rep, 0, N);

    // loss
    loss_pass<<<(N + 511) / 512, 320, 0, stream>>>(rep, labels, N, colSum, pickedSum, cntRed);
    finalize_kernel<<<1, 64, 0, stream>>>(colSum, cntRed, pickedSum, N, lossOut);
}

// Round 8
// 396.667 us; speedup vs baseline: 5.4252x; 1.0379x over previous
//
#include <hip/hip_runtime.h>
#include <hip/hip_bf16.h>
#include <hip/hip_fp16.h>

#define NCLS 40

typedef __attribute__((ext_vector_type(8))) _Float16 half8;
typedef __attribute__((ext_vector_type(2))) _Float16 half2h;
union H2U { half2h h; unsigned u; };

// ---------------- CSR build: bucketed counting sort ----------------
#define EPB 16384     // edges per level-1 block
#define MAXB1 128     // max level-1 blocks (E <= MAXB1*EPB)
#define MAXNB 104     // max buckets (N <= MAXNB*1024)

__global__ void bucket_hist(const int* __restrict__ dst, int E, int nb,
                            int* __restrict__ blockHist) {
    __shared__ int cnt[4][MAXNB];   // 4-way replicated to cut LDS-atomic collisions
    int t = threadIdx.x;  // 256
    for (int i = t; i < 4 * MAXNB; i += 256) cnt[i / MAXNB][i % MAXNB] = 0;
    __syncthreads();
    int bk = t & 3;
    int base = blockIdx.x * EPB;
    int end = min(base + EPB, E);
    for (int i = base + t; i < end; i += 256) atomicAdd(&cnt[bk][dst[i] >> 10], 1);
    __syncthreads();
    for (int i = t; i < nb; i += 256)
        blockHist[blockIdx.x * nb + i] = cnt[0][i] + cnt[1][i] + cnt[2][i] + cnt[3][i];
}

// also zeroes the 512-byte reduction scratch (replaces a memset dispatch)
__global__ void bucket_scan(const int* __restrict__ blockHist, int nB1, int nb,
                            int* __restrict__ blockBase, int* __restrict__ bucketOffs,
                            int* __restrict__ offs, int N, int E, int* __restrict__ red32) {
    __shared__ int h[MAXB1 * MAXNB];
    __shared__ int btot[MAXNB];
    __shared__ int boffs[MAXNB + 1];
    int t = threadIdx.x;  // 128
    if (t < 128) red32[t] = 0;
    int total = nB1 * nb;
    for (int i = t; i < total; i += 128) h[i] = blockHist[i];
    __syncthreads();
    for (int b = t; b < nb; b += 128) {
        int run = 0;
        for (int i = 0; i < nB1; ++i) { int v = h[i * nb + b]; h[i * nb + b] = run; run += v; }
        btot[b] = run;
    }
    __syncthreads();
    if (t == 0) {
        int run = 0;
        for (int b = 0; b < nb; ++b) { boffs[b] = run; run += btot[b]; }
        boffs[nb] = run;
    }
    __syncthreads();
    for (int b = t; b < nb; b += 128) {
        int bo = boffs[b];
        for (int i = 0; i < nB1; ++i) h[i * nb + b] += bo;
    }
    __syncthreads();
    for (int i = t; i < total; i += 128) blockBase[i] = h[i];
    for (int b = t; b <= nb; b += 128) bucketOffs[b] = boffs[b];
    if (t == 0) offs[N] = E;
}

__global__ void bucket_place(const int* __restrict__ src, const int* __restrict__ dst, int E,
                             int nb, const int* __restrict__ blockBase,
                             unsigned* __restrict__ tmp) {
    __shared__ int cur[MAXNB];
    int t = threadIdx.x;  // 256
    for (int i = t; i < nb; i += 256) cur[i] = blockBase[blockIdx.x * nb + i];
    __syncthreads();
    int base = blockIdx.x * EPB;
    int end = min(base + EPB, E);
    for (int i = base + t; i < end; i += 256) {
        int d = dst[i];
        int s = src[i];
        unsigned pack = ((unsigned)(d & 1023) << 17) | (unsigned)s;  // src < 2^17
        int pos = atomicAdd(&cur[d >> 10], 1);
        tmp[pos] = pack;
    }
}

__global__ __launch_bounds__(512) void bucket_finalize(const unsigned* __restrict__ tmp,
                                                       const int* __restrict__ bucketOffs,
                                                       int N, int* __restrict__ offs,
                                                       int* __restrict__ esrc) {
    __shared__ int cnt[1024];
    __shared__ int wsum[8];
    int b = blockIdx.x;
    int t = threadIdx.x;  // 512
    int bstart = bucketOffs[b], bend = bucketOffs[b + 1];
    cnt[t] = 0;
    cnt[t + 512] = 0;
    __syncthreads();
    for (int i = bstart + t; i < bend; i += 512) atomicAdd(&cnt[tmp[i] >> 17], 1);
    __syncthreads();
    int c0 = cnt[2 * t], c1 = cnt[2 * t + 1];
    int s = c0 + c1;
    int lane = t & 63, w = t >> 6;
    int ssc = s;
    for (int off = 1; off < 64; off <<= 1) {
        int v = __shfl_up(ssc, off, 64);
        if (lane >= off) ssc += v;
    }
    if (lane == 63) wsum[w] = ssc;
    __syncthreads();
    int wo = 0;
#pragma unroll
    for (int k = 0; k < 8; ++k)
        if (k < w) wo += wsum[k];
    int excl = (ssc - s) + wo + bstart;
    __syncthreads();
    int node0 = (b << 10) + 2 * t;
    if (node0 < N) offs[node0] = excl;
    if (node0 + 1 < N) offs[node0 + 1] = excl + c0;
    cnt[2 * t] = excl;
    cnt[2 * t + 1] = excl + c0;
    __syncthreads();
    for (int i = bstart + t; i < bend; i += 512) {
        unsigned p = tmp[i];
        int pos = atomicAdd(&cnt[p >> 17], 1);
        esrc[pos] = (int)(p & 0x1FFFFu);
    }
}

// ---------------- dense X[N,64] @ W[64,64] -> fp16 out ----------------------
__global__ __launch_bounds__(256, 4) void gemm_h(const float* __restrict__ X,
                                                 const float* __restrict__ W,
                                                 _Float16* __restrict__ out, int N) {
    int lane = threadIdx.x & 63;
    int waveId = (blockIdx.x * blockDim.x + threadIdx.x) >> 6;
    int nWaves = (gridDim.x * blockDim.x) >> 6;

    float w[64];
#pragma unroll
    for (int k = 0; k < 64; ++k) w[k] = W[k * 64 + lane];

    int row = waveId;
    float xv = (row < N) ? X[(size_t)row * 64 + lane] : 0.f;
    for (; row < N; row += nWaves) {
        int nrow = row + nWaves;
        float nxt = (nrow < N) ? X[(size_t)nrow * 64 + lane] : 0.f;
        float acc = 0.f;
#pragma unroll
        for (int k = 0; k < 64; ++k) {
            float xk = __uint_as_float(__builtin_amdgcn_readlane(__float_as_uint(xv), k));
            acc = fmaf(xk, w[k], acc);
        }
        out[(size_t)row * 64 + lane] = (_Float16)acc;
        xv = nxt;
    }
}

// ---------------- plain aggregation over fp16 rows [N,64] -------------------
__global__ void agg64h_kernel(const _Float16* __restrict__ t, const int* __restrict__ offs,
                              const int* __restrict__ esrc, const float* __restrict__ bias,
                              _Float16* __restrict__ out, int N) {
    int gid = blockIdx.x * blockDim.x + threadIdx.x;
    int node = gid >> 6;
    if (node >= N) return;
    int lane = threadIdx.x & 63;
    int sub = lane >> 3;   // edge slot 0..7
    int c8 = lane & 7;     // col octet (8 halfs = 16 B)
    int beg = offs[node], end = offs[node + 1];
    float a[8];
#pragma unroll
    for (int k = 0; k < 8; ++k) a[k] = 0.f;
    int j = beg + sub;
    for (; j + 8 < end; j += 16) {
        int s0 = esrc[j];
        int s1 = esrc[j + 8];
        half8 v0 = *(const half8*)(t + (size_t)s0 * 64 + c8 * 8);
        half8 v1 = *(const half8*)(t + (size_t)s1 * 64 + c8 * 8);
#pragma unroll
        for (int k = 0; k < 8; ++k) a[k] += (float)v0[k] + (float)v1[k];
    }
    if (j < end) {
        int s0 = esrc[j];
        half8 v0 = *(const half8*)(t + (size_t)s0 * 64 + c8 * 8);
#pragma unroll
        for (int k = 0; k < 8; ++k) a[k] += (float)v0[k];
    }
#pragma unroll
    for (int k = 0; k < 8; ++k) {
        a[k] += __shfl_down(a[k], 32, 64);
        a[k] += __shfl_down(a[k], 16, 64);
        a[k] += __shfl_down(a[k], 8, 64);
    }
    if (sub == 0) {
        half8 hv;
#pragma unroll
        for (int k = 0; k < 8; ++k) {
            float v = fmaxf(a[k] + bias[c8 * 8 + k], 0.f);  // bias + relu
            hv[k] = (_Float16)v;
        }
        *(half8*)(out + (size_t)node * 64 + c8 * 8) = hv;
    }
}

// ---------------- fused aggregation + GEMV epilogue (v_dot2_f32_f16) --------
// Gather fp16 rows -> reduced row on lanes 0..7 -> pack to half2 -> GEMV via
// 32 readlane + 32 fdot2 against packed-fp16 W column, 2 accumulators.
__global__ __launch_bounds__(256, 4) void fused_agg_gemm(
        const _Float16* __restrict__ t, const int* __restrict__ offs,
        const int* __restrict__ esrc, const float* __restrict__ aggBias, int doRelu,
        const float* __restrict__ W, const float* __restrict__ gemmBias, int FO,
        void* __restrict__ out, int outHalf, int N) {
    int lane = threadIdx.x & 63;
    int waveId = (blockIdx.x * blockDim.x + threadIdx.x) >> 6;
    int nWaves = (gridDim.x * blockDim.x) >> 6;
    int sub = lane >> 3;
    int c8 = lane & 7;
    int cl = lane < FO ? lane : 0;

    H2U wh[32];
#pragma unroll
    for (int j = 0; j < 32; ++j)
        wh[j].h = half2h{(_Float16)W[(2 * j) * FO + cl], (_Float16)W[(2 * j + 1) * FO + cl]};
    float gb = 0.f;
    if (gemmBias != nullptr && lane < FO) gb = gemmBias[lane];
    float ab[8];
#pragma unroll
    for (int k = 0; k < 8; ++k) ab[k] = (aggBias != nullptr) ? aggBias[c8 * 8 + k] : 0.f;

    float* outF = (float*)out;
    _Float16* outH = (_Float16*)out;

    for (int node = waveId; node < N; node += nWaves) {
        int beg = offs[node], end = offs[node + 1];
        float a[8];
#pragma unroll
        for (int k = 0; k < 8; ++k) a[k] = 0.f;
        int j = beg + sub;
        for (; j + 8 < end; j += 16) {
            int s0 = esrc[j];
            int s1 = esrc[j + 8];
            half8 v0 = *(const half8*)(t + (size_t)s0 * 64 + c8 * 8);
            half8 v1 = *(const half8*)(t + (size_t)s1 * 64 + c8 * 8);
#pragma unroll
            for (int k = 0; k < 8; ++k) a[k] += (float)v0[k] + (float)v1[k];
        }
        if (j < end) {
            int s0 = esrc[j];
            half8 v0 = *(const half8*)(t + (size_t)s0 * 64 + c8 * 8);
#pragma unroll
            for (int k = 0; k < 8; ++k) a[k] += (float)v0[k];
        }
#pragma unroll
        for (int k = 0; k < 8; ++k) {
            a[k] += __shfl_down(a[k], 32, 64);
            a[k] += __shfl_down(a[k], 16, 64);
            a[k] += __shfl_down(a[k], 8, 64);
            a[k] += ab[k];                       // only lanes 0..7 matter below
            if (doRelu) a[k] = fmaxf(a[k], 0.f);
        }
        // pack reduced row (lanes 0..7, 8 regs) into 4 half2 regs
        H2U p[4];
#pragma unroll
        for (int q = 0; q < 4; ++q)
            p[q].h = half2h{(_Float16)a[2 * q], (_Float16)a[2 * q + 1]};
        // GEMV: K-pair j -> row[2j],row[2j+1] on lane j>>2, packed reg j&3
        float y0 = gb, y1 = 0.f;
#pragma unroll
        for (int j2 = 0; j2 < 32; j2 += 2) {
            H2U r0, r1;
            r0.u = __builtin_amdgcn_readlane(p[j2 & 3].u, j2 >> 2);
            r1.u = __builtin_amdgcn_readlane(p[(j2 + 1) & 3].u, (j2 + 1) >> 2);
            y0 = __builtin_amdgcn_fdot2(r0.h, wh[j2].h, y0, false);
            y1 = __builtin_amdgcn_fdot2(r1.h, wh[j2 + 1].h, y1, false);
        }
        float y = y0 + y1;
        if (lane < FO) {
            if (outHalf) outH[(size_t)node * FO + lane] = (_Float16)y;
            else         outF[(size_t)node * FO + lane] = y;
        }
    }
}

// ---------------- loss ----------------
__global__ void loss_pass(const float* __restrict__ rep, const int* __restrict__ labels, int N,
                          double* __restrict__ colSum, double* __restrict__ pickedSum,
                          int* __restrict__ cnt) {
    const int G = 8;
    const int ROWS = 512;
    int t = threadIdx.x;  // blockDim = 320
    int c = t % NCLS;
    int g = t / NCLS;
    int base = blockIdx.x * ROWS;
    int lim = min(base + ROWS, N);
    double sumLoc = 0.0, pickLoc = 0.0;
    int cntLoc = 0;
    for (int r = base + g; r < lim; r += G) {
        float v = rep[(size_t)r * NCLS + c];
        sumLoc += exp((double)v);
        if (labels[r] == c) { pickLoc += (double)v; cntLoc++; }
    }
    __shared__ double colP[G][NCLS];
    __shared__ int cntP[G][NCLS];
    __shared__ double waveP[5];
    colP[g][c] = sumLoc;
    cntP[g][c] = cntLoc;
    __syncthreads();
    if (g == 0) {
        double tot = 0.0;
        int ctot = 0;
        for (int gg = 0; gg < G; ++gg) { tot += colP[gg][c]; ctot += cntP[gg][c]; }
        atomicAdd(&colSum[c], tot);
        if (ctot) atomicAdd(&cnt[c], ctot);
    }
    double wv = pickLoc;
    for (int off = 32; off; off >>= 1) wv += __shfl_down(wv, off, 64);
    if ((t & 63) == 0) waveP[t >> 6] = wv;
    __syncthreads();
    if (t == 0) {
        double s = 0.0;
        for (int i = 0; i < 5; ++i) s += waveP[i];
        atomicAdd(pickedSum, s);
    }
}

__global__ void finalize_kernel(const double* __restrict__ colSum, const int* __restrict__ cnt,
                                const double* __restrict__ pickedSum, int N,
                                float* __restrict__ lossOut) {
    int t = threadIdx.x;
    double term = 0.0;
    if (t < NCLS) term = (double)cnt[t] * log(colSum[t]);
    for (int off = 32; off; off >>= 1) term += __shfl_down(term, off, 64);
    if (t == 0) lossOut[0] = (float)((term - pickedSum[0]) / (double)N);
}

extern "C" void kernel_launch(void* const* d_in, const int* in_sizes, int n_in,
                              void* d_out, int out_size, void* d_ws, size_t ws_size,
                              hipStream_t stream) {
    const float* features = (const float*)d_in[0];
    const float* W0 = (const float*)d_in[1];
    const float* b0 = (const float*)d_in[2];
    const float* W1 = (const float*)d_in[3];
    const float* b1 = (const float*)d_in[4];
    const float* W2 = (const float*)d_in[5];
    const float* b2 = (const float*)d_in[6];
    const int* src = (const int*)d_in[7];
    const int* dst = (const int*)d_in[8];
    const int* labels = (const int*)d_in[9];

    const int N = in_sizes[0] / 64;
    const int E = in_sizes[7];
    const int NC = in_sizes[6];  // 40

    char* ws = (char*)d_ws;
    size_t off = 0;
    auto alloc = [&](size_t bytes) -> void* {
        void* p = ws + off;
        off = (off + bytes + 255) & ~(size_t)255;
        return p;
    };
    int* offs      = (int*)alloc((size_t)(N + 1) * 4);
    int* esrc      = (int*)alloc((size_t)E * 4);
    _Float16* t0   = (_Float16*)alloc((size_t)N * 64 * 2);   // gemm0 out
    _Float16* t1   = (_Float16*)alloc((size_t)N * 64 * 2);   // fusedA out; aliases tmp
    _Float16* h2   = (_Float16*)alloc((size_t)N * 64 * 2);   // aggB out
    int* blockHist = (int*)alloc((size_t)MAXB1 * MAXNB * 4);
    int* blockBase = (int*)alloc((size_t)MAXB1 * MAXNB * 4);
    int* bucketOffs= (int*)alloc((size_t)(MAXNB + 1) * 4);
    char* red      = (char*)alloc(512);
    double* colSum    = (double*)red;
    double* pickedSum = (double*)(red + 320);
    int* cntRed       = (int*)(red + 328);

    unsigned* tmp = (unsigned*)t1;  // E*4 = 6.8 MB <= N*64*2 = 12.8 MB; dead before fusedA

    float* rep = (float*)d_out;
    float* lossOut = rep + (size_t)N * NC;

    const int nb  = (N + 1023) >> 10;
    const int nB1 = (E + EPB - 1) / EPB;

    bucket_hist<<<nB1, 256, 0, stream>>>(dst, E, nb, blockHist);
    bucket_scan<<<1, 128, 0, stream>>>(blockHist, nB1, nb, blockBase, bucketOffs, offs, N, E,
                                       (int*)red);
    bucket_place<<<nB1, 256, 0, stream>>>(src, dst, E, nb, blockBase, tmp);
    bucket_finalize<<<nb, 512, 0, stream>>>(tmp, bucketOffs, N, offs, esrc);

    const int nodeWaveBlocks = (N * 64 + 255) / 256;  // one wave per node

    // layer 0 gemm: t0 = fp16(X@W0)
    gemm_h<<<2048, 256, 0, stream>>>(features, W0, t0, N);
    // fused layer0-agg + layer1-gemm: t1 = fp16(relu(S@t0 + b0) @ W1)
    fused_agg_gemm<<<2048, 256, 0, stream>>>(t0, offs, esrc, b0, 1, W1, nullptr, 64, t1, 1, N);
    // layer1 agg: h2 = fp16(relu(S@t1 + b1))
    agg64h_kernel<<<nodeWaveBlocks, 256, 0, stream>>>(t1, offs, esrc, b1, h2, N);
    // fused layer2: rep = (S@h2)@W2 + b2   [fp32 out]
    fused_agg_gemm<<<2048, 256, 0, stream>>>(h2, offs, esrc, nullptr, 0, W2, b2, NC, rep, 0, N);

    // loss
    loss_pass<<<(N + 511) / 512, 320, 0, stream>>>(rep, labels, N, colSum, pickedSum, cntRed);
    finalize_kernel<<<1, 64, 0, stream>>>(colSum, cntRed, pickedSum, N, lossOut);
}